// Round 14
// baseline (608.931 us; speedup 1.0000x reference)
//
#include <hip/hip_runtime.h>

typedef unsigned short u16;
typedef u16 u16x4 __attribute__((ext_vector_type(4)));
typedef u16 u16x8 __attribute__((ext_vector_type(8)));
typedef float f32x4 __attribute__((ext_vector_type(4)));
typedef __bf16 bf16x8 __attribute__((ext_vector_type(8)));

#define S_LEN 2048
#define HIDDEN_D 4096
#define NHEADS 32
#define QLORA 1536
#define KVLORA 512
#define ROPED 64
#define NOPED 128
#define VDIM 128
#define QHD 192
#define SCALING_F 0.07216878364870323f

__device__ __forceinline__ u16 f2bf(float x) {
  union { float f; unsigned u; } v; v.f = x;
  unsigned r = v.u + 0x7fffu + ((v.u >> 16) & 1u);
  return (u16)(r >> 16);
}
__device__ __forceinline__ float bf2f(u16 x) {
  union { unsigned u; float f; } v; v.u = ((unsigned)x) << 16; return v.f;
}

__device__ __forceinline__ f32x4 mfma_bf16(u16x8 a, u16x8 b, f32x4 c) {
  return __builtin_amdgcn_mfma_f32_16x16x32_bf16(
      __builtin_bit_cast(bf16x8, a), __builtin_bit_cast(bf16x8, b), c, 0, 0, 0);
}

// ---------------- fused fp32->bf16 convert for all 5 linear tensors ----------------
// segments (blocks): [0,8192) hidden; [8192,14336) w_q_a; [14336,16640) w_kv_a;
// [16640,20736) w_kv_b; [20736,37120) w_o.  All sizes exact multiples of 1024 elems.
__global__ __launch_bounds__(256) void cvt_all(
    const float* __restrict__ hsrc, u16* __restrict__ Hb,
    const float* __restrict__ wqa, const float* __restrict__ wkva, u16* __restrict__ WqaKva,
    const float* __restrict__ wkvb, u16* __restrict__ Wkvb,
    const float* __restrict__ wo, u16* __restrict__ Wo)
{
  const int b = blockIdx.x, t = threadIdx.x;
  const float* src; u16* dst; size_t idx;
  if (b < 8192)       { src = hsrc; dst = Hb;     idx = (size_t)b * 256 + t; }
  else if (b < 14336) { src = wqa;  dst = WqaKva; idx = (size_t)(b - 8192) * 256 + t; }
  else if (b < 16640) { src = wkva; dst = WqaKva + (size_t)QLORA * HIDDEN_D; idx = (size_t)(b - 14336) * 256 + t; }
  else if (b < 20736) { src = wkvb; dst = Wkvb;   idx = (size_t)(b - 16640) * 256 + t; }
  else                { src = wo;   dst = Wo;     idx = (size_t)(b - 20736) * 256 + t; }
  f32x4 v = ((const f32x4*)src)[idx];
  u16x4 o;
  o[0] = f2bf(v[0]); o[1] = f2bf(v[1]); o[2] = f2bf(v[2]); o[3] = f2bf(v[3]);
  ((u16x4*)dst)[idx] = o;
}

// ---------------- Wqb convert + row permute ----------------
// Reorders each head's output cols to [x(=src 128..159) | y(=src 160..191) | nope(src 0..127)]
// so rope pairs (x,y) land 32 cols apart -> same lane, acc[m][n] & acc[m][n+2] in the GEMM.
__global__ __launch_bounds__(256) void cvt_qperm(const float* __restrict__ in,
                                                 u16* __restrict__ out) {
  const size_t idx = (size_t)blockIdx.x * 256 + threadIdx.x;  // quad index
  const int row = (int)(idx / 384), c4 = (int)(idx % 384);
  const int h = row / 192, d = row - h * 192;
  const int newd = (d >= 128) ? (d - 128) : (d + 64);
  f32x4 v = ((const f32x4*)in)[idx];
  u16x4 o;
  o[0] = f2bf(v[0]); o[1] = f2bf(v[1]); o[2] = f2bf(v[2]); o[3] = f2bf(v[3]);
  ((u16x4*)out)[(size_t)(h * 192 + newd) * 384 + c4] = o;
}

// ============ GEMM core (R9-proven): A bf16 * B bf16^T, reg-staged dbuf LDS ============

#define GEMM_PROLOGUE(BIDX)                                                    \
  __shared__ u16 sA[2][128 * 64];                                              \
  __shared__ u16 sB[2][128 * 64];                                              \
  const int tid = threadIdx.x;                                                 \
  const int wid = tid >> 6, lane = tid & 63;                                   \
  const int lr = lane & 15, lg = lane >> 4;                                    \
  const int nbn = (N + 127) >> 7;                                              \
  const int bx = (BIDX) % nbn, by = (BIDX) / nbn;                              \
  const int bm = by << 7, bn = bx << 7;                                        \
  const int wm = (wid >> 1) << 6, wn = (wid & 1) << 6;                         \
  const int kbase = blockIdx.y * Ks;                                           \
  f32x4 acc[4][4] = {};                                                        \
  u16x8 areg[4], breg[4];                                                      \
  auto loadA = [&](int k0) {                                                   \
    _Pragma("unroll")                                                          \
    for (int i = 0; i < 4; ++i) {                                              \
      int chunk = i * 256 + tid;                                               \
      int row = chunk >> 3, c8 = chunk & 7;                                    \
      int gr = bm + row; if (gr >= M) gr = M - 1;                              \
      areg[i] = *(const u16x8*)(A + (size_t)gr * lda + k0 + (c8 << 3));        \
    }                                                                          \
  };                                                                           \
  auto loadB = [&](int k0) {                                                   \
    _Pragma("unroll")                                                          \
    for (int i = 0; i < 4; ++i) {                                              \
      int chunk = i * 256 + tid;                                               \
      int n = chunk >> 3, c8 = chunk & 7;                                      \
      int gn = bn + n; if (gn >= N) gn = N - 1;                                \
      breg[i] = *(const u16x8*)(B + (size_t)gn * ldb + k0 + (c8 << 3));        \
    }                                                                          \
  };                                                                           \
  auto writeAB = [&](int buf) {                                                \
    _Pragma("unroll")                                                          \
    for (int i = 0; i < 4; ++i) {                                              \
      *(u16x8*)&sA[buf][(i * 256 + tid) * 8] = areg[i];                        \
      *(u16x8*)&sB[buf][(i * 256 + tid) * 8] = breg[i];                        \
    }                                                                          \
  };                                                                           \
  auto compute = [&](int buf) {                                                \
    const u16* pa = sA[buf];                                                   \
    const u16* pb = sB[buf];                                                   \
    _Pragma("unroll")                                                          \
    for (int ks = 0; ks < 2; ++ks) {                                           \
      const int kof = ks * 32 + lg * 8;                                        \
      u16x8 av[4], bv[4];                                                      \
      _Pragma("unroll")                                                        \
      for (int m = 0; m < 4; ++m) av[m] = *(const u16x8*)&pa[(wm + m * 16 + lr) * 64 + kof]; \
      _Pragma("unroll")                                                        \
      for (int n = 0; n < 4; ++n) bv[n] = *(const u16x8*)&pb[(wn + n * 16 + lr) * 64 + kof]; \
      _Pragma("unroll")                                                        \
      for (int m = 0; m < 4; ++m)                                              \
        _Pragma("unroll")                                                      \
        for (int n = 0; n < 4; ++n)                                            \
          acc[m][n] = mfma_bf16(av[m], bv[n], acc[m][n]);                      \
    }                                                                          \
  };                                                                           \
  const int nk = Ks >> 6;                                                      \
  loadA(kbase); loadB(kbase);                                                  \
  writeAB(0);                                                                  \
  __syncthreads();                                                             \
  for (int t = 0; t < nk; ++t) {                                               \
    const int cur = t & 1;                                                     \
    if (t + 1 < nk) { loadA(kbase + ((t + 1) << 6)); loadB(kbase + ((t + 1) << 6)); } \
    compute(cur);                                                              \
    if (t + 1 < nk) { writeAB(cur ^ 1); }                                      \
    __syncthreads();                                                           \
  }

// ---------------- GEMM -> fp32 C (fused q_a+kv_a, w_o) ----------------
__global__ __launch_bounds__(256, 2) void gemm_ff(
    const u16* __restrict__ A, const u16* __restrict__ B, float* __restrict__ C,
    int M, int N, int Ks, int lda, int ldb, int ldc)
{
  C += (size_t)blockIdx.y * M * ldc;
  GEMM_PROLOGUE(blockIdx.x)
#pragma unroll
  for (int m = 0; m < 4; ++m) {
    const int row0 = bm + wm + m * 16 + (lg << 2);
#pragma unroll
    for (int n = 0; n < 4; ++n) {
      const int col = bn + wn + n * 16 + lr;
      if (col < N) {
#pragma unroll
        for (int r = 0; r < 4; ++r)
          C[(size_t)(row0 + r) * ldc + col] = acc[m][n][r];
      }
    }
  }
}

// ---------------- merged q_b + kv_b GEMM ----------------
// blocks [0,768): q = qlatn @ Wqb(perm)^T with fused rope+scale+layout -> Qb
// blocks [768,1792): kv = klatn @ Wkvb^T with fused split+transpose -> Knope, Vt
__global__ __launch_bounds__(256, 2) void gemm_qb_kvb(
    const u16* __restrict__ qlatn, const u16* __restrict__ Wqb,
    const float* __restrict__ cosp, const float* __restrict__ sinp, u16* __restrict__ Qb,
    const u16* __restrict__ klatn, const u16* __restrict__ Wkvb,
    u16* __restrict__ Knope, u16* __restrict__ Vt)
{
  if (blockIdx.x < 768) {
    const u16* A = qlatn; const u16* B = Wqb;
    const int M = 2048, N = 6144, Ks = 1536, lda = 1536, ldb = 1536;
    GEMM_PROLOGUE(blockIdx.x)
    // fused rope epilogue: per-head col layout is [x(32)|y(32)|nope(128)] (cvt_qperm)
#pragma unroll
    for (int m = 0; m < 4; ++m) {
      const int row0 = bm + wm + m * 16 + (lg << 2);
#pragma unroll
      for (int n = 0; n < 2; ++n) {
        const int col = bn + wn + n * 16 + lr;
        const int h = col / 192, tc = col - h * 192;
        if (tc < 32) {  // x slot; partner y at acc[m][n+2]
#pragma unroll
          for (int r = 0; r < 4; ++r) {
            const int s = row0 + r;
            const float cx = cosp[s * 64 + tc],      sx = sinp[s * 64 + tc];
            const float cy = cosp[s * 64 + tc + 32], sy = sinp[s * 64 + tc + 32];
            const float xv = acc[m][n][r], yv = acc[m][n + 2][r];
            Qb[((size_t)h * 2048 + s) * QHD + tc]      = f2bf((xv * cx - yv * sx) * SCALING_F);
            Qb[((size_t)h * 2048 + s) * QHD + tc + 32] = f2bf((yv * cy + xv * sy) * SCALING_F);
          }
        }
      }
#pragma unroll
      for (int n = 0; n < 4; ++n) {
        const int col = bn + wn + n * 16 + lr;
        const int h = col / 192, tc = col - h * 192;
        if (tc >= 64) {  // nope slot
#pragma unroll
          for (int r = 0; r < 4; ++r) {
            const int s = row0 + r;
            Qb[((size_t)h * 2048 + s) * QHD + tc] = f2bf(acc[m][n][r] * SCALING_F);
          }
        }
      }
    }
  } else {
    const u16* A = klatn; const u16* B = Wkvb;
    const int M = 2048, N = 8192, Ks = 512, lda = 512, ldb = 512;
    GEMM_PROLOGUE(blockIdx.x - 768)
#pragma unroll
    for (int m = 0; m < 4; ++m) {
      const int row0 = bm + wm + m * 16 + (lg << 2);
#pragma unroll
      for (int n = 0; n < 4; ++n) {
        const int col = bn + wn + n * 16 + lr;
        const int h = col >> 8, c = col & 255;
        if (c < 128) {
#pragma unroll
          for (int r = 0; r < 4; ++r)
            Knope[((size_t)h * 2048 + row0 + r) * 128 + c] = f2bf(acc[m][n][r]);
        } else {
          u16x4 v;
          v[0] = f2bf(acc[m][n][0]); v[1] = f2bf(acc[m][n][1]);
          v[2] = f2bf(acc[m][n][2]); v[3] = f2bf(acc[m][n][3]);
          *(u16x4*)&Vt[((size_t)h * 128 + (c - 128)) * 2048 + row0] = v;
        }
      }
    }
  }
}

// ---------------- merged norm epilogues over the fused a-proj partials ----------------
// blocks [0,2048): RMS over cols 0..1535 -> qlatn (bf16)
// blocks [2048,4096): RMS(512) + rope(64) over cols 1536..2111 -> klatn, krot
__global__ __launch_bounds__(256) void norm_fused(
    const float* __restrict__ qkv_part,
    const float* __restrict__ q_a_ln, const float* __restrict__ kv_a_ln,
    const float* __restrict__ cosp, const float* __restrict__ sinp,
    u16* __restrict__ qlatn, u16* __restrict__ klatn, u16* __restrict__ krot)
{
  const size_t PSTRIDE = (size_t)S_LEN * 2112;
  __shared__ float sb[4];
  if (blockIdx.x < 2048) {
    const int row = blockIdx.x;
    const float* x = qkv_part + (size_t)row * 2112;
    float ss = 0.f;
    for (int i = threadIdx.x * 4; i < 1536; i += 1024) {
      f32x4 v = *(const f32x4*)&x[i];
      f32x4 v2 = *(const f32x4*)&x[PSTRIDE + i];
      v[0] += v2[0]; v[1] += v2[1]; v[2] += v2[2]; v[3] += v2[3];
      ss += v[0] * v[0] + v[1] * v[1] + v[2] * v[2] + v[3] * v[3];
    }
#pragma unroll
    for (int off = 32; off >= 1; off >>= 1) ss += __shfl_xor(ss, off, 64);
    if ((threadIdx.x & 63) == 0) sb[threadIdx.x >> 6] = ss;
    __syncthreads();
    const float inv = rsqrtf((sb[0] + sb[1] + sb[2] + sb[3]) / 1536.0f + 1e-6f);
    u16* o = qlatn + (size_t)row * 1536;
    for (int i = threadIdx.x * 4; i < 1536; i += 1024) {
      f32x4 v = *(const f32x4*)&x[i];
      f32x4 v2 = *(const f32x4*)&x[PSTRIDE + i];
      v[0] += v2[0]; v[1] += v2[1]; v[2] += v2[2]; v[3] += v2[3];
      f32x4 wv = *(const f32x4*)&q_a_ln[i];
      u16x4 u;
      u[0] = f2bf(v[0] * inv * wv[0]); u[1] = f2bf(v[1] * inv * wv[1]);
      u[2] = f2bf(v[2] * inv * wv[2]); u[3] = f2bf(v[3] * inv * wv[3]);
      *(u16x4*)&o[i] = u;
    }
  } else {
    const int s = blockIdx.x - 2048;
    const float* x = qkv_part + 1536 + (size_t)s * 2112;
    const int i2 = threadIdx.x * 2;
    float a = x[i2] + x[PSTRIDE + i2];
    float b = x[i2 + 1] + x[PSTRIDE + i2 + 1];
    float ss = a * a + b * b;
#pragma unroll
    for (int off = 32; off >= 1; off >>= 1) ss += __shfl_xor(ss, off, 64);
    if ((threadIdx.x & 63) == 0) sb[threadIdx.x >> 6] = ss;
    __syncthreads();
    const float inv = rsqrtf((sb[0] + sb[1] + sb[2] + sb[3]) / 512.0f + 1e-6f);
    klatn[(size_t)s * 512 + i2]     = f2bf(a * inv * kv_a_ln[i2]);
    klatn[(size_t)s * 512 + i2 + 1] = f2bf(b * inv * kv_a_ln[i2 + 1]);
    if (threadIdx.x < 64) {
      const int d = threadIdx.x;
      const float xr = x[512 + d] + x[PSTRIDE + 512 + d];
      const int dp = (d < 32) ? (d + 32) : (d - 32);
      const float rrabs = x[512 + dp] + x[PSTRIDE + 512 + dp];
      const float rr = (d < 32) ? -rrabs : rrabs;
      krot[(size_t)s * 64 + d] = f2bf(xr * cosp[s * 64 + d] + rr * sinp[s * 64 + d]);
    }
  }
}

// ---------------- flash attention (causal), 4 waves, QBLK=128, KVBLK=64 ----------------
// EXACT R1/R8/R12 structure (measured 244us / 40MB fetch): linear LDS, natural
// block order, no setprio, no barrier. DO NOT MODIFY — fragile cache-lockstep regime.
__global__ __launch_bounds__(256, 2) void flash_kernel(
    const u16* __restrict__ Qb, const u16* __restrict__ Krot,
    const u16* __restrict__ Knope, const u16* __restrict__ Vt,
    u16* __restrict__ attnb)
{
  const int h = blockIdx.x & 31, qt = blockIdx.x >> 5;
  const int q0 = qt << 7;
  __shared__ u16 sK[64][QHD];      // [kv][rope(64)|nope(128)]
  __shared__ u16 sV[VDIM][64];     // V^T [d][kv]
  __shared__ u16 sP[4][32][64];    // per-wave P
  const int tid = threadIdx.x;
  const int wid = tid >> 6, lane = tid & 63;
  const int lr = lane & 15, lg = lane >> 4;

  u16x8 qf[2][6];
#pragma unroll
  for (int m = 0; m < 2; ++m) {
    const int row = q0 + wid * 32 + m * 16 + lr;
#pragma unroll
    for (int kk = 0; kk < 6; ++kk)
      qf[m][kk] = *(const u16x8*)&Qb[((size_t)h * 2048 + row) * QHD + kk * 32 + lg * 8];
  }

  f32x4 acc[2][8] = {};
  float mx[2][4], ls[2][4];
#pragma unroll
  for (int m = 0; m < 2; ++m)
#pragma unroll
    for (int r = 0; r < 4; ++r) { mx[m][r] = -1e30f; ls[m][r] = 0.f; }

  const int nkv = q0 + 128;
  u16x8 kreg[6], vreg[4];

  auto loadKV = [&](int kv0) {
#pragma unroll
    for (int i = 0; i < 6; ++i) {
      const int chunk = i * 256 + tid;
      const int row = chunk / 24, cc = chunk % 24;
      const u16* src = (cc < 8)
          ? &Krot[(size_t)(kv0 + row) * 64 + cc * 8]
          : &Knope[((size_t)h * 2048 + kv0 + row) * 128 + (cc - 8) * 8];
      kreg[i] = *(const u16x8*)src;
    }
#pragma unroll
    for (int i = 0; i < 4; ++i) {
      const int chunk = i * 256 + tid;
      const int d = chunk >> 3, c = chunk & 7;
      vreg[i] = *(const u16x8*)&Vt[((size_t)h * VDIM + d) * 2048 + kv0 + c * 8];
    }
  };

  loadKV(0);
  for (int kv0 = 0; kv0 < nkv; kv0 += 64) {
    __syncthreads();  // prior compute done before overwriting sK/sV
    u16* kbase = &sK[0][0];
#pragma unroll
    for (int i = 0; i < 6; ++i) *(u16x8*)&kbase[(size_t)(i * 256 + tid) * 8] = kreg[i];
    u16* vbase = &sV[0][0];
#pragma unroll
    for (int i = 0; i < 4; ++i) *(u16x8*)&vbase[(size_t)(i * 256 + tid) * 8] = vreg[i];
    __syncthreads();
    if (kv0 + 64 < nkv) loadKV(kv0 + 64);  // prefetch overlaps compute

    // S^ = Q K^T  (per wave: 32 q rows x 64 kv)
    f32x4 sc[2][4] = {};
#pragma unroll
    for (int kk = 0; kk < 6; ++kk) {
      u16x8 bfr[4];
#pragma unroll
      for (int n = 0; n < 4; ++n) bfr[n] = *(const u16x8*)&sK[n * 16 + lr][kk * 32 + lg * 8];
#pragma unroll
      for (int m = 0; m < 2; ++m)
#pragma unroll
        for (int n = 0; n < 4; ++n)
          sc[m][n] = mfma_bf16(qf[m][kk], bfr[n], sc[m][n]);
    }

    // causal mask
    if (kv0 + 63 > q0 + wid * 32) {
#pragma unroll
      for (int m = 0; m < 2; ++m)
#pragma unroll
        for (int n = 0; n < 4; ++n) {
          const int kv = kv0 + n * 16 + lr;
#pragma unroll
          for (int r = 0; r < 4; ++r) {
            const int rowq = q0 + wid * 32 + m * 16 + lg * 4 + r;
            if (kv > rowq) sc[m][n][r] = -1e30f;
          }
        }
    }

    // online softmax (rows live in (lg, reg); reduce across lr lanes)
#pragma unroll
    for (int m = 0; m < 2; ++m) {
      float rs[4];
#pragma unroll
      for (int r = 0; r < 4; ++r) {
        float v = fmaxf(fmaxf(sc[m][0][r], sc[m][1][r]), fmaxf(sc[m][2][r], sc[m][3][r]));
#pragma unroll
        for (int off = 1; off < 16; off <<= 1) v = fmaxf(v, __shfl_xor(v, off, 64));
        const float mnew = fmaxf(mx[m][r], v);
        const float alpha = __expf(mx[m][r] - mnew);
        mx[m][r] = mnew;
        ls[m][r] *= alpha;
#pragma unroll
        for (int df = 0; df < 8; ++df) acc[m][df][r] *= alpha;
        rs[r] = 0.f;
      }
#pragma unroll
      for (int n = 0; n < 4; ++n)
#pragma unroll
        for (int r = 0; r < 4; ++r) {
          const float p = __expf(sc[m][n][r] - mx[m][r]);
          rs[r] += p;
          sP[wid][m * 16 + lg * 4 + r][n * 16 + lr] = f2bf(p);
        }
#pragma unroll
      for (int r = 0; r < 4; ++r) {
        float v = rs[r];
#pragma unroll
        for (int off = 1; off < 16; off <<= 1) v += __shfl_xor(v, off, 64);
        ls[m][r] += v;
      }
    }

    // PV: acc += P * V
#pragma unroll
    for (int ks = 0; ks < 2; ++ks) {
      u16x8 pf0 = *(const u16x8*)&sP[wid][lr][ks * 32 + lg * 8];
      u16x8 pf1 = *(const u16x8*)&sP[wid][16 + lr][ks * 32 + lg * 8];
#pragma unroll
      for (int df = 0; df < 8; ++df) {
        u16x8 vf = *(const u16x8*)&sV[df * 16 + lr][ks * 32 + lg * 8];
        acc[0][df] = mfma_bf16(pf0, vf, acc[0][df]);
        acc[1][df] = mfma_bf16(pf1, vf, acc[1][df]);
      }
    }
  }

  // epilogue: attn(s, h*128+d) bf16
#pragma unroll
  for (int m = 0; m < 2; ++m)
#pragma unroll
    for (int df = 0; df < 8; ++df) {
      const int col = h * 128 + df * 16 + lr;
#pragma unroll
      for (int r = 0; r < 4; ++r) {
        const int row = q0 + wid * 32 + m * 16 + lg * 4 + r;
        attnb[(size_t)row * 4096 + col] = f2bf(acc[m][df][r] / ls[m][r]);
      }
    }
}

extern "C" void kernel_launch(void* const* d_in, const int* in_sizes, int n_in,
                              void* d_out, int out_size, void* d_ws, size_t ws_size,
                              hipStream_t stream) {
  (void)in_sizes; (void)n_in; (void)out_size; (void)ws_size;
  const float* hidden  = (const float*)d_in[0];
  const float* cosp    = (const float*)d_in[1];
  const float* sinp    = (const float*)d_in[2];
  const float* w_q_a   = (const float*)d_in[3];
  const float* q_a_ln  = (const float*)d_in[4];
  const float* w_q_b   = (const float*)d_in[5];
  const float* w_kv_a  = (const float*)d_in[6];
  const float* kv_a_ln = (const float*)d_in[7];
  const float* w_kv_b  = (const float*)d_in[8];
  const float* w_o     = (const float*)d_in[9];
  float* out = (float*)d_out;

  char* p = (char*)d_ws;
  auto alloc = [&](size_t bytes) { char* r = p; p += (bytes + 255) & ~(size_t)255; return r; };
  u16* Hb      = (u16*)alloc((size_t)S_LEN * HIDDEN_D * 2);
  u16* qlatn   = (u16*)alloc((size_t)S_LEN * QLORA * 2);
  u16* klatn   = (u16*)alloc((size_t)S_LEN * KVLORA * 2);
  u16* krot    = (u16*)alloc((size_t)S_LEN * ROPED * 2);
  u16* Qb      = (u16*)alloc((size_t)NHEADS * S_LEN * QHD * 2);
  u16* Knope   = (u16*)alloc((size_t)NHEADS * S_LEN * NOPED * 2);
  u16* Vt      = (u16*)alloc((size_t)NHEADS * VDIM * S_LEN * 2);
  u16* attnb   = (u16*)alloc((size_t)S_LEN * 4096 * 2);
  u16* WqaKva  = (u16*)alloc((size_t)2112 * HIDDEN_D * 2);   // [w_q_a(1536); w_kv_a(576)]
  u16* Wqb     = (u16*)alloc((size_t)6144 * QLORA * 2);      // row-permuted
  u16* Wkvb    = (u16*)alloc((size_t)8192 * KVLORA * 2);
  u16* Wo      = (u16*)alloc((size_t)HIDDEN_D * 4096 * 2);
  float* qkv_part = (float*)alloc((size_t)2 * S_LEN * 2112 * 4);  // 2 split-K partials

  // 1. fused converts (hidden + 4 weights) and Wqb permute-convert
  cvt_all<<<37120, 256, 0, stream>>>(hidden, Hb, w_q_a, w_kv_a, WqaKva, w_kv_b, Wkvb, w_o, Wo);
  cvt_qperm<<<9216, 256, 0, stream>>>(w_q_b, Wqb);
  // 2. fused [q_lat | ckv] partials = Hb @ WqaKva^T  (2048 x 2112, K=4096 split 2)
  gemm_ff<<<dim3(16 * 17, 2), 256, 0, stream>>>(Hb, WqaKva, qkv_part, 2048, 2112, 2048, 4096, 4096, 2112);
  // 3. merged RMS(q_lat) + RMS/rope(ckv) epilogues
  norm_fused<<<4096, 256, 0, stream>>>(qkv_part, q_a_ln, kv_a_ln, cosp, sinp, qlatn, klatn, krot);
  // 4. merged q_b (fused rope -> Qb) + kv_b (fused split/transpose -> Knope,Vt)
  gemm_qb_kvb<<<768 + 1024, 256, 0, stream>>>(qlatn, Wqb, cosp, sinp, Qb, klatn, Wkvb, Knope, Vt);
  // 5. causal flash attention (exact R12 known-good structure)
  flash_kernel<<<512, 256, 0, stream>>>(Qb, krot, Knope, Vt, attnb);
  // 6. out = attn @ Wo^T  (2048 x 4096, K=4096, fp32 out)
  gemm_ff<<<dim3(16 * 32, 1), 256, 0, stream>>>(attnb, Wo, out, 2048, 4096, 4096, 4096, 4096, 4096);
}

// Round 16
// 598.763 us; speedup vs baseline: 1.0170x; 1.0170x over previous
//
#include <hip/hip_runtime.h>

typedef unsigned short u16;
typedef u16 u16x4 __attribute__((ext_vector_type(4)));
typedef u16 u16x8 __attribute__((ext_vector_type(8)));
typedef float f32x4 __attribute__((ext_vector_type(4)));
typedef __bf16 bf16x8 __attribute__((ext_vector_type(8)));

#define S_LEN 2048
#define HIDDEN_D 4096
#define NHEADS 32
#define QLORA 1536
#define KVLORA 512
#define ROPED 64
#define NOPED 128
#define VDIM 128
#define QHD 192
#define SCALING_F 0.07216878364870323f

__device__ __forceinline__ u16 f2bf(float x) {
  union { float f; unsigned u; } v; v.f = x;
  unsigned r = v.u + 0x7fffu + ((v.u >> 16) & 1u);
  return (u16)(r >> 16);
}
__device__ __forceinline__ float bf2f(u16 x) {
  union { unsigned u; float f; } v; v.u = ((unsigned)x) << 16; return v.f;
}

__device__ __forceinline__ f32x4 mfma_bf16(u16x8 a, u16x8 b, f32x4 c) {
  return __builtin_amdgcn_mfma_f32_16x16x32_bf16(
      __builtin_bit_cast(bf16x8, a), __builtin_bit_cast(bf16x8, b), c, 0, 0, 0);
}

// ---------------- fp32 -> bf16 convert (vector) ----------------
__global__ __launch_bounds__(256) void cvt_kernel(const float* __restrict__ in,
                                                  u16* __restrict__ out, int n4) {
  int i = blockIdx.x * 256 + threadIdx.x;
  if (i >= n4) return;
  f32x4 v = ((const f32x4*)in)[i];
  u16x4 o;
  o[0] = f2bf(v[0]); o[1] = f2bf(v[1]); o[2] = f2bf(v[2]); o[3] = f2bf(v[3]);
  ((u16x4*)out)[i] = o;
}

// ============ GEMM core (R9-proven): A bf16 * B bf16^T, reg-staged dbuf LDS ============

#define GEMM_PROLOGUE()                                                        \
  __shared__ u16 sA[2][128 * 64];                                              \
  __shared__ u16 sB[2][128 * 64];                                              \
  const int tid = threadIdx.x;                                                 \
  const int wid = tid >> 6, lane = tid & 63;                                   \
  const int lr = lane & 15, lg = lane >> 4;                                    \
  const int nbn = (N + 127) >> 7;                                              \
  const int bx = blockIdx.x % nbn, by = blockIdx.x / nbn;                      \
  const int bm = by << 7, bn = bx << 7;                                        \
  const int wm = (wid >> 1) << 6, wn = (wid & 1) << 6;                         \
  const int kbase = blockIdx.y * Ks;                                           \
  f32x4 acc[4][4] = {};                                                        \
  u16x8 areg[4], breg[4];                                                      \
  auto loadA = [&](int k0) {                                                   \
    _Pragma("unroll")                                                          \
    for (int i = 0; i < 4; ++i) {                                              \
      int chunk = i * 256 + tid;                                               \
      int row = chunk >> 3, c8 = chunk & 7;                                    \
      int gr = bm + row; if (gr >= M) gr = M - 1;                              \
      areg[i] = *(const u16x8*)(A + (size_t)gr * lda + k0 + (c8 << 3));        \
    }                                                                          \
  };                                                                           \
  auto loadB = [&](int k0) {                                                   \
    _Pragma("unroll")                                                          \
    for (int i = 0; i < 4; ++i) {                                              \
      int chunk = i * 256 + tid;                                               \
      int n = chunk >> 3, c8 = chunk & 7;                                      \
      int gn = bn + n; if (gn >= N) gn = N - 1;                                \
      breg[i] = *(const u16x8*)(B + (size_t)gn * ldb + k0 + (c8 << 3));        \
    }                                                                          \
  };                                                                           \
  auto writeAB = [&](int buf) {                                                \
    _Pragma("unroll")                                                          \
    for (int i = 0; i < 4; ++i) {                                              \
      *(u16x8*)&sA[buf][(i * 256 + tid) * 8] = areg[i];                        \
      *(u16x8*)&sB[buf][(i * 256 + tid) * 8] = breg[i];                        \
    }                                                                          \
  };                                                                           \
  auto compute = [&](int buf) {                                                \
    const u16* pa = sA[buf];                                                   \
    const u16* pb = sB[buf];                                                   \
    _Pragma("unroll")                                                          \
    for (int ks = 0; ks < 2; ++ks) {                                           \
      const int kof = ks * 32 + lg * 8;                                        \
      u16x8 av[4], bv[4];                                                      \
      _Pragma("unroll")                                                        \
      for (int m = 0; m < 4; ++m) av[m] = *(const u16x8*)&pa[(wm + m * 16 + lr) * 64 + kof]; \
      _Pragma("unroll")                                                        \
      for (int n = 0; n < 4; ++n) bv[n] = *(const u16x8*)&pb[(wn + n * 16 + lr) * 64 + kof]; \
      _Pragma("unroll")                                                        \
      for (int m = 0; m < 4; ++m)                                              \
        _Pragma("unroll")                                                      \
        for (int n = 0; n < 4; ++n)                                            \
          acc[m][n] = mfma_bf16(av[m], bv[n], acc[m][n]);                      \
    }                                                                          \
  };                                                                           \
  const int nk = Ks >> 6;                                                      \
  loadA(kbase); loadB(kbase);                                                  \
  writeAB(0);                                                                  \
  __syncthreads();                                                             \
  for (int t = 0; t < nk; ++t) {                                               \
    const int cur = t & 1;                                                     \
    if (t + 1 < nk) { loadA(kbase + ((t + 1) << 6)); loadB(kbase + ((t + 1) << 6)); } \
    compute(cur);                                                              \
    if (t + 1 < nk) { writeAB(cur ^ 1); }                                      \
    __syncthreads();                                                           \
  }

// ---------------- GEMM -> fp32 C (fused q_a+kv_a, w_o) ----------------
__global__ __launch_bounds__(256, 2) void gemm_ff(
    const u16* __restrict__ A, const u16* __restrict__ B, float* __restrict__ C,
    int M, int N, int Ks, int lda, int ldb, int ldc)
{
  C += (size_t)blockIdx.y * M * ldc;
  GEMM_PROLOGUE()
#pragma unroll
  for (int m = 0; m < 4; ++m) {
    const int row0 = bm + wm + m * 16 + (lg << 2);
#pragma unroll
    for (int n = 0; n < 4; ++n) {
      const int col = bn + wn + n * 16 + lr;
      if (col < N) {
#pragma unroll
        for (int r = 0; r < 4; ++r)
          C[(size_t)(row0 + r) * ldc + col] = acc[m][n][r];
      }
    }
  }
}

// ---------------- GEMM -> bf16 C (q_b) ----------------
__global__ __launch_bounds__(256, 2) void gemm_fb(
    const u16* __restrict__ A, const u16* __restrict__ B, u16* __restrict__ C,
    int M, int N, int Ks, int lda, int ldb, int ldc)
{
  GEMM_PROLOGUE()
#pragma unroll
  for (int m = 0; m < 4; ++m) {
    const int row0 = bm + wm + m * 16 + (lg << 2);
#pragma unroll
    for (int n = 0; n < 4; ++n) {
      const int col = bn + wn + n * 16 + lr;
#pragma unroll
      for (int r = 0; r < 4; ++r)
        C[(size_t)(row0 + r) * ldc + col] = f2bf(acc[m][n][r]);
    }
  }
}

// ---------------- kv_b GEMM with fused split+transpose epilogue ----------------
// C[s][h*256+c]: c<128 -> Knope[(h*2048+s)*128+c]; c>=128 -> Vt[(h*128+c-128)*2048+s].
__global__ __launch_bounds__(256, 2) void gemm_kvb(
    const u16* __restrict__ A, const u16* __restrict__ B,
    u16* __restrict__ Knope, u16* __restrict__ Vt,
    int M, int N, int Ks, int lda, int ldb)
{
  GEMM_PROLOGUE()
#pragma unroll
  for (int m = 0; m < 4; ++m) {
    const int row0 = bm + wm + m * 16 + (lg << 2);
#pragma unroll
    for (int n = 0; n < 4; ++n) {
      const int col = bn + wn + n * 16 + lr;
      const int h = col >> 8, c = col & 255;
      if (c < 128) {
#pragma unroll
        for (int r = 0; r < 4; ++r)
          Knope[((size_t)h * 2048 + row0 + r) * 128 + c] = f2bf(acc[m][n][r]);
      } else {
        u16x4 v;
        v[0] = f2bf(acc[m][n][0]); v[1] = f2bf(acc[m][n][1]);
        v[2] = f2bf(acc[m][n][2]); v[3] = f2bf(acc[m][n][3]);
        *(u16x4*)&Vt[((size_t)h * 128 + (c - 128)) * 2048 + row0] = v;
      }
    }
  }
}

// ---------------- RMS norm rows over summed split-K partials (fp32 -> bf16) ----------------
__global__ __launch_bounds__(256) void rms_kernel(const float* __restrict__ X,
                                                  const float* __restrict__ w,
                                                  u16* __restrict__ out, int D, int ldx,
                                                  int nparts, size_t pstride) {
  const int row = blockIdx.x;
  const float* x = X + (size_t)row * ldx;
  __shared__ float sb[4];
  float ss = 0.f;
  for (int i = threadIdx.x * 4; i < D; i += 1024) {
    f32x4 v = *(const f32x4*)&x[i];
    for (int pp = 1; pp < nparts; ++pp) {
      f32x4 v2 = *(const f32x4*)&x[pp * pstride + i];
      v[0] += v2[0]; v[1] += v2[1]; v[2] += v2[2]; v[3] += v2[3];
    }
    ss += v[0] * v[0] + v[1] * v[1] + v[2] * v[2] + v[3] * v[3];
  }
#pragma unroll
  for (int off = 32; off >= 1; off >>= 1) ss += __shfl_xor(ss, off, 64);
  if ((threadIdx.x & 63) == 0) sb[threadIdx.x >> 6] = ss;
  __syncthreads();
  const float inv = rsqrtf((sb[0] + sb[1] + sb[2] + sb[3]) / (float)D + 1e-6f);
  u16* o = out + (size_t)row * D;
  for (int i = threadIdx.x * 4; i < D; i += 1024) {
    f32x4 v = *(const f32x4*)&x[i];
    for (int pp = 1; pp < nparts; ++pp) {
      f32x4 v2 = *(const f32x4*)&x[pp * pstride + i];
      v[0] += v2[0]; v[1] += v2[1]; v[2] += v2[2]; v[3] += v2[3];
    }
    f32x4 wv = *(const f32x4*)&w[i];
    u16x4 u;
    u[0] = f2bf(v[0] * inv * wv[0]); u[1] = f2bf(v[1] * inv * wv[1]);
    u[2] = f2bf(v[2] * inv * wv[2]); u[3] = f2bf(v[3] * inv * wv[3]);
    *(u16x4*)&o[i] = u;
  }
}

// ---------------- ckv epilogue over split-K partials: RMS(512) + rope(64) ----------------
__global__ __launch_bounds__(256) void ckv_epi_kernel(const float* __restrict__ ckv,
    const float* __restrict__ w, const float* __restrict__ cosp, const float* __restrict__ sinp,
    u16* __restrict__ klatn, u16* __restrict__ krot, int ldx, int nparts, size_t pstride) {
  const int s = blockIdx.x;
  const float* x = ckv + (size_t)s * ldx;
  __shared__ float sb[4];
  const int i2 = threadIdx.x * 2;
  float a = 0.f, b = 0.f;
  for (int pp = 0; pp < nparts; ++pp) {
    a += x[pp * pstride + i2];
    b += x[pp * pstride + i2 + 1];
  }
  float ss = a * a + b * b;
#pragma unroll
  for (int off = 32; off >= 1; off >>= 1) ss += __shfl_xor(ss, off, 64);
  if ((threadIdx.x & 63) == 0) sb[threadIdx.x >> 6] = ss;
  __syncthreads();
  const float inv = rsqrtf((sb[0] + sb[1] + sb[2] + sb[3]) / 512.0f + 1e-6f);
  klatn[(size_t)s * 512 + i2]     = f2bf(a * inv * w[i2]);
  klatn[(size_t)s * 512 + i2 + 1] = f2bf(b * inv * w[i2 + 1]);
  if (threadIdx.x < 64) {
    const int d = threadIdx.x;
    float xr = 0.f, rrabs = 0.f;
    for (int pp = 0; pp < nparts; ++pp) {
      xr += x[pp * pstride + 512 + d];
      rrabs += x[pp * pstride + 512 + ((d < 32) ? (d + 32) : (d - 32))];
    }
    const float rr = (d < 32) ? -rrabs : rrabs;
    krot[(size_t)s * 64 + d] = f2bf(xr * cosp[s * 64 + d] + rr * sinp[s * 64 + d]);
  }
}

// ---------------- q epilogue (bf16 in): rope + scale + [rope|nope] layout, bf16 ----------------
__global__ __launch_bounds__(256) void q_epi_kernel(const u16* __restrict__ q_raw,
    const float* __restrict__ cosp, const float* __restrict__ sinp, u16* __restrict__ Qb) {
  const int s = blockIdx.x;
  const u16* x = q_raw + (size_t)s * 6144;
  for (int idx = threadIdx.x; idx < 6144; idx += 256) {
    const int h = idx / 192, d = idx - h * 192;
    float v;
    if (d < 64) {
      const float xr = bf2f(x[h * 192 + 128 + d]);
      const float rr = (d < 32) ? -bf2f(x[h * 192 + 160 + d]) : bf2f(x[h * 192 + 96 + d]);
      v = xr * cosp[s * 64 + d] + rr * sinp[s * 64 + d];
    } else {
      v = bf2f(x[h * 192 + d - 64]);
    }
    Qb[((size_t)h * 2048 + s) * QHD + d] = f2bf(v * SCALING_F);
  }
}

// ---------------- flash attention (causal), 4 waves, QBLK=128, KVBLK=64 ----------------
// EXACT R1/R8/R12 structure (measured 244us / 40MB fetch): linear LDS, natural
// block order, no setprio, no barrier. DO NOT MODIFY — fragile cache-lockstep regime.
__global__ __launch_bounds__(256, 2) void flash_kernel(
    const u16* __restrict__ Qb, const u16* __restrict__ Krot,
    const u16* __restrict__ Knope, const u16* __restrict__ Vt,
    u16* __restrict__ attnb)
{
  const int h = blockIdx.x & 31, qt = blockIdx.x >> 5;
  const int q0 = qt << 7;
  __shared__ u16 sK[64][QHD];      // [kv][rope(64)|nope(128)]
  __shared__ u16 sV[VDIM][64];     // V^T [d][kv]
  __shared__ u16 sP[4][32][64];    // per-wave P
  const int tid = threadIdx.x;
  const int wid = tid >> 6, lane = tid & 63;
  const int lr = lane & 15, lg = lane >> 4;

  u16x8 qf[2][6];
#pragma unroll
  for (int m = 0; m < 2; ++m) {
    const int row = q0 + wid * 32 + m * 16 + lr;
#pragma unroll
    for (int kk = 0; kk < 6; ++kk)
      qf[m][kk] = *(const u16x8*)&Qb[((size_t)h * 2048 + row) * QHD + kk * 32 + lg * 8];
  }

  f32x4 acc[2][8] = {};
  float mx[2][4], ls[2][4];
#pragma unroll
  for (int m = 0; m < 2; ++m)
#pragma unroll
    for (int r = 0; r < 4; ++r) { mx[m][r] = -1e30f; ls[m][r] = 0.f; }

  const int nkv = q0 + 128;
  u16x8 kreg[6], vreg[4];

  auto loadKV = [&](int kv0) {
#pragma unroll
    for (int i = 0; i < 6; ++i) {
      const int chunk = i * 256 + tid;
      const int row = chunk / 24, cc = chunk % 24;
      const u16* src = (cc < 8)
          ? &Krot[(size_t)(kv0 + row) * 64 + cc * 8]
          : &Knope[((size_t)h * 2048 + kv0 + row) * 128 + (cc - 8) * 8];
      kreg[i] = *(const u16x8*)src;
    }
#pragma unroll
    for (int i = 0; i < 4; ++i) {
      const int chunk = i * 256 + tid;
      const int d = chunk >> 3, c = chunk & 7;
      vreg[i] = *(const u16x8*)&Vt[((size_t)h * VDIM + d) * 2048 + kv0 + c * 8];
    }
  };

  loadKV(0);
  for (int kv0 = 0; kv0 < nkv; kv0 += 64) {
    __syncthreads();  // prior compute done before overwriting sK/sV
    u16* kbase = &sK[0][0];
#pragma unroll
    for (int i = 0; i < 6; ++i) *(u16x8*)&kbase[(size_t)(i * 256 + tid) * 8] = kreg[i];
    u16* vbase = &sV[0][0];
#pragma unroll
    for (int i = 0; i < 4; ++i) *(u16x8*)&vbase[(size_t)(i * 256 + tid) * 8] = vreg[i];
    __syncthreads();
    if (kv0 + 64 < nkv) loadKV(kv0 + 64);  // prefetch overlaps compute

    // S^ = Q K^T  (per wave: 32 q rows x 64 kv)
    f32x4 sc[2][4] = {};
#pragma unroll
    for (int kk = 0; kk < 6; ++kk) {
      u16x8 bfr[4];
#pragma unroll
      for (int n = 0; n < 4; ++n) bfr[n] = *(const u16x8*)&sK[n * 16 + lr][kk * 32 + lg * 8];
#pragma unroll
      for (int m = 0; m < 2; ++m)
#pragma unroll
        for (int n = 0; n < 4; ++n)
          sc[m][n] = mfma_bf16(qf[m][kk], bfr[n], sc[m][n]);
    }

    // causal mask
    if (kv0 + 63 > q0 + wid * 32) {
#pragma unroll
      for (int m = 0; m < 2; ++m)
#pragma unroll
        for (int n = 0; n < 4; ++n) {
          const int kv = kv0 + n * 16 + lr;
#pragma unroll
          for (int r = 0; r < 4; ++r) {
            const int rowq = q0 + wid * 32 + m * 16 + lg * 4 + r;
            if (kv > rowq) sc[m][n][r] = -1e30f;
          }
        }
    }

    // online softmax (rows live in (lg, reg); reduce across lr lanes)
#pragma unroll
    for (int m = 0; m < 2; ++m) {
      float rs[4];
#pragma unroll
      for (int r = 0; r < 4; ++r) {
        float v = fmaxf(fmaxf(sc[m][0][r], sc[m][1][r]), fmaxf(sc[m][2][r], sc[m][3][r]));
#pragma unroll
        for (int off = 1; off < 16; off <<= 1) v = fmaxf(v, __shfl_xor(v, off, 64));
        const float mnew = fmaxf(mx[m][r], v);
        const float alpha = __expf(mx[m][r] - mnew);
        mx[m][r] = mnew;
        ls[m][r] *= alpha;
#pragma unroll
        for (int df = 0; df < 8; ++df) acc[m][df][r] *= alpha;
        rs[r] = 0.f;
      }
#pragma unroll
      for (int n = 0; n < 4; ++n)
#pragma unroll
        for (int r = 0; r < 4; ++r) {
          const float p = __expf(sc[m][n][r] - mx[m][r]);
          rs[r] += p;
          sP[wid][m * 16 + lg * 4 + r][n * 16 + lr] = f2bf(p);
        }
#pragma unroll
      for (int r = 0; r < 4; ++r) {
        float v = rs[r];
#pragma unroll
        for (int off = 1; off < 16; off <<= 1) v += __shfl_xor(v, off, 64);
        ls[m][r] += v;
      }
    }

    // PV: acc += P * V
#pragma unroll
    for (int ks = 0; ks < 2; ++ks) {
      u16x8 pf0 = *(const u16x8*)&sP[wid][lr][ks * 32 + lg * 8];
      u16x8 pf1 = *(const u16x8*)&sP[wid][16 + lr][ks * 32 + lg * 8];
#pragma unroll
      for (int df = 0; df < 8; ++df) {
        u16x8 vf = *(const u16x8*)&sV[df * 16 + lr][ks * 32 + lg * 8];
        acc[0][df] = mfma_bf16(pf0, vf, acc[0][df]);
        acc[1][df] = mfma_bf16(pf1, vf, acc[1][df]);
      }
    }
  }

  // epilogue: attn(s, h*128+d) bf16
#pragma unroll
  for (int m = 0; m < 2; ++m)
#pragma unroll
    for (int df = 0; df < 8; ++df) {
      const int col = h * 128 + df * 16 + lr;
#pragma unroll
      for (int r = 0; r < 4; ++r) {
        const int row = q0 + wid * 32 + m * 16 + lg * 4 + r;
        attnb[(size_t)row * 4096 + col] = f2bf(acc[m][df][r] / ls[m][r]);
      }
    }
}

extern "C" void kernel_launch(void* const* d_in, const int* in_sizes, int n_in,
                              void* d_out, int out_size, void* d_ws, size_t ws_size,
                              hipStream_t stream) {
  (void)in_sizes; (void)n_in; (void)out_size; (void)ws_size;
  const float* hidden  = (const float*)d_in[0];
  const float* cosp    = (const float*)d_in[1];
  const float* sinp    = (const float*)d_in[2];
  const float* w_q_a   = (const float*)d_in[3];
  const float* q_a_ln  = (const float*)d_in[4];
  const float* w_q_b   = (const float*)d_in[5];
  const float* w_kv_a  = (const float*)d_in[6];
  const float* kv_a_ln = (const float*)d_in[7];
  const float* w_kv_b  = (const float*)d_in[8];
  const float* w_o     = (const float*)d_in[9];
  float* out = (float*)d_out;

  char* p = (char*)d_ws;
  auto alloc = [&](size_t bytes) { char* r = p; p += (bytes + 255) & ~(size_t)255; return r; };
  u16* Hb      = (u16*)alloc((size_t)S_LEN * HIDDEN_D * 2);
  u16* qlatn   = (u16*)alloc((size_t)S_LEN * QLORA * 2);
  u16* klatn   = (u16*)alloc((size_t)S_LEN * KVLORA * 2);
  u16* krot    = (u16*)alloc((size_t)S_LEN * ROPED * 2);
  u16* Qb      = (u16*)alloc((size_t)NHEADS * S_LEN * QHD * 2);
  u16* Knope   = (u16*)alloc((size_t)NHEADS * S_LEN * NOPED * 2);
  u16* Vt      = (u16*)alloc((size_t)NHEADS * VDIM * S_LEN * 2);
  u16* attnb   = (u16*)alloc((size_t)S_LEN * 4096 * 2);
  u16* WqaKva  = (u16*)alloc((size_t)2112 * HIDDEN_D * 2);   // [w_q_a(1536); w_kv_a(576)]
  u16* Wqb     = (u16*)alloc((size_t)6144 * QLORA * 2);
  u16* Wkvb    = (u16*)alloc((size_t)8192 * KVLORA * 2);
  u16* Wo      = (u16*)alloc((size_t)HIDDEN_D * 4096 * 2);
  u16* qraw16  = (u16*)alloc((size_t)S_LEN * 6144 * 2);
  float* qkv_part = (float*)alloc((size_t)2 * S_LEN * 2112 * 4);  // 2 split-K partials

  // 1. activations + weights -> bf16 (w_q_a and w_kv_a into one contiguous B)
  cvt_kernel<<<(S_LEN * HIDDEN_D / 4 + 255) / 256, 256, 0, stream>>>(hidden, Hb, S_LEN * HIDDEN_D / 4);
  cvt_kernel<<<(QLORA * HIDDEN_D / 4 + 255) / 256, 256, 0, stream>>>(w_q_a, WqaKva, QLORA * HIDDEN_D / 4);
  cvt_kernel<<<(576 * HIDDEN_D / 4 + 255) / 256, 256, 0, stream>>>(w_kv_a, WqaKva + (size_t)QLORA * HIDDEN_D, 576 * HIDDEN_D / 4);
  cvt_kernel<<<(6144 * QLORA / 4 + 255) / 256, 256, 0, stream>>>(w_q_b, Wqb, 6144 * QLORA / 4);
  cvt_kernel<<<(8192 * KVLORA / 4 + 255) / 256, 256, 0, stream>>>(w_kv_b, Wkvb, 8192 * KVLORA / 4);
  cvt_kernel<<<(HIDDEN_D * 4096 / 4 + 255) / 256, 256, 0, stream>>>(w_o, Wo, HIDDEN_D * 4096 / 4);

  // 2. fused [q_lat | ckv] partials = Hb @ WqaKva^T  (2048 x 2112, K=4096 split 2)
  gemm_ff<<<dim3(16 * 17, 2), 256, 0, stream>>>(Hb, WqaKva, qkv_part, 2048, 2112, 2048, 4096, 4096, 2112);
  // 3. RMS(sum of q_lat partials, cols 0..1535) -> bf16
  rms_kernel<<<2048, 256, 0, stream>>>(qkv_part, q_a_ln, qlatn, 1536, 2112, 2, (size_t)S_LEN * 2112);
  // 4. RMS(sum of ckv partials, cols 1536..2111) + rope(k_rot)
  ckv_epi_kernel<<<2048, 256, 0, stream>>>(qkv_part + 1536, kv_a_ln, cosp, sinp, klatn, krot, 2112, 2, (size_t)S_LEN * 2112);
  // 5. q = qlatn @ Wqb^T  (2048 x 6144, K=1536, bf16 out)
  gemm_fb<<<dim3(16 * 48, 1), 256, 0, stream>>>(qlatn, Wqb, qraw16, 2048, 6144, 1536, 1536, 1536, 6144);
  // 6. rope+scale+layout -> Qb
  q_epi_kernel<<<2048, 256, 0, stream>>>(qraw16, cosp, sinp, Qb);
  // 7. kv = klatn @ Wkvb^T with fused split+transpose -> Knope, Vt (bf16)
  gemm_kvb<<<dim3(16 * 64, 1), 256, 0, stream>>>(klatn, Wkvb, Knope, Vt, 2048, 8192, 512, 512, 512);
  // 8. causal flash attention (exact R8/R12 known-good structure)
  flash_kernel<<<512, 256, 0, stream>>>(Qb, krot, Knope, Vt, attnb);
  // 9. out = attn @ Wo^T  (2048 x 4096, K=4096, fp32 out)
  gemm_ff<<<dim3(16 * 32, 1), 256, 0, stream>>>(attnb, Wo, out, 2048, 4096, 4096, 4096, 4096, 4096);
}

// Round 17
// 586.017 us; speedup vs baseline: 1.0391x; 1.0218x over previous
//
#include <hip/hip_runtime.h>

typedef unsigned short u16;
typedef u16 u16x4 __attribute__((ext_vector_type(4)));
typedef u16 u16x8 __attribute__((ext_vector_type(8)));
typedef float f32x4 __attribute__((ext_vector_type(4)));
typedef __bf16 bf16x8 __attribute__((ext_vector_type(8)));

#define S_LEN 2048
#define HIDDEN_D 4096
#define NHEADS 32
#define QLORA 1536
#define KVLORA 512
#define ROPED 64
#define NOPED 128
#define VDIM 128
#define QHD 192
#define SCALING_F 0.07216878364870323f

__device__ __forceinline__ u16 f2bf(float x) {
  union { float f; unsigned u; } v; v.f = x;
  unsigned r = v.u + 0x7fffu + ((v.u >> 16) & 1u);
  return (u16)(r >> 16);
}
__device__ __forceinline__ float bf2f(u16 x) {
  union { unsigned u; float f; } v; v.u = ((unsigned)x) << 16; return v.f;
}

__device__ __forceinline__ f32x4 mfma_bf16(u16x8 a, u16x8 b, f32x4 c) {
  return __builtin_amdgcn_mfma_f32_16x16x32_bf16(
      __builtin_bit_cast(bf16x8, a), __builtin_bit_cast(bf16x8, b), c, 0, 0, 0);
}

// ---------------- fused fp32->bf16 convert for 5 linear tensors (R14-verified) ----------------
// segments (blocks): [0,8192) hidden; [8192,14336) w_q_a; [14336,16640) w_kv_a;
// [16640,20736) w_kv_b; [20736,37120) w_o.  All sizes exact multiples of 1024 elems.
__global__ __launch_bounds__(256) void cvt_all(
    const float* __restrict__ hsrc, u16* __restrict__ Hb,
    const float* __restrict__ wqa, const float* __restrict__ wkva, u16* __restrict__ WqaKva,
    const float* __restrict__ wkvb, u16* __restrict__ Wkvb,
    const float* __restrict__ wo, u16* __restrict__ Wo)
{
  const int b = blockIdx.x, t = threadIdx.x;
  const float* src; u16* dst; size_t idx;
  if (b < 8192)       { src = hsrc; dst = Hb;     idx = (size_t)b * 256 + t; }
  else if (b < 14336) { src = wqa;  dst = WqaKva; idx = (size_t)(b - 8192) * 256 + t; }
  else if (b < 16640) { src = wkva; dst = WqaKva + (size_t)QLORA * HIDDEN_D; idx = (size_t)(b - 14336) * 256 + t; }
  else if (b < 20736) { src = wkvb; dst = Wkvb;   idx = (size_t)(b - 16640) * 256 + t; }
  else                { src = wo;   dst = Wo;     idx = (size_t)(b - 20736) * 256 + t; }
  f32x4 v = ((const f32x4*)src)[idx];
  u16x4 o;
  o[0] = f2bf(v[0]); o[1] = f2bf(v[1]); o[2] = f2bf(v[2]); o[3] = f2bf(v[3]);
  ((u16x4*)dst)[idx] = o;
}

// ---------------- plain fp32 -> bf16 convert (w_q_b) ----------------
__global__ __launch_bounds__(256) void cvt_kernel(const float* __restrict__ in,
                                                  u16* __restrict__ out, int n4) {
  int i = blockIdx.x * 256 + threadIdx.x;
  if (i >= n4) return;
  f32x4 v = ((const f32x4*)in)[i];
  u16x4 o;
  o[0] = f2bf(v[0]); o[1] = f2bf(v[1]); o[2] = f2bf(v[2]); o[3] = f2bf(v[3]);
  ((u16x4*)out)[i] = o;
}

// ============ GEMM core (R9-proven): A bf16 * B bf16^T, reg-staged dbuf LDS ============

#define GEMM_PROLOGUE()                                                        \
  __shared__ u16 sA[2][128 * 64];                                              \
  __shared__ u16 sB[2][128 * 64];                                              \
  const int tid = threadIdx.x;                                                 \
  const int wid = tid >> 6, lane = tid & 63;                                   \
  const int lr = lane & 15, lg = lane >> 4;                                    \
  const int nbn = (N + 127) >> 7;                                              \
  const int bx = blockIdx.x % nbn, by = blockIdx.x / nbn;                      \
  const int bm = by << 7, bn = bx << 7;                                        \
  const int wm = (wid >> 1) << 6, wn = (wid & 1) << 6;                         \
  const int kbase = blockIdx.y * Ks;                                           \
  f32x4 acc[4][4] = {};                                                        \
  u16x8 areg[4], breg[4];                                                      \
  auto loadA = [&](int k0) {                                                   \
    _Pragma("unroll")                                                          \
    for (int i = 0; i < 4; ++i) {                                              \
      int chunk = i * 256 + tid;                                               \
      int row = chunk >> 3, c8 = chunk & 7;                                    \
      int gr = bm + row; if (gr >= M) gr = M - 1;                              \
      areg[i] = *(const u16x8*)(A + (size_t)gr * lda + k0 + (c8 << 3));        \
    }                                                                          \
  };                                                                           \
  auto loadB = [&](int k0) {                                                   \
    _Pragma("unroll")                                                          \
    for (int i = 0; i < 4; ++i) {                                              \
      int chunk = i * 256 + tid;                                               \
      int n = chunk >> 3, c8 = chunk & 7;                                      \
      int gn = bn + n; if (gn >= N) gn = N - 1;                                \
      breg[i] = *(const u16x8*)(B + (size_t)gn * ldb + k0 + (c8 << 3));        \
    }                                                                          \
  };                                                                           \
  auto writeAB = [&](int buf) {                                                \
    _Pragma("unroll")                                                          \
    for (int i = 0; i < 4; ++i) {                                              \
      *(u16x8*)&sA[buf][(i * 256 + tid) * 8] = areg[i];                        \
      *(u16x8*)&sB[buf][(i * 256 + tid) * 8] = breg[i];                        \
    }                                                                          \
  };                                                                           \
  auto compute = [&](int buf) {                                                \
    const u16* pa = sA[buf];                                                   \
    const u16* pb = sB[buf];                                                   \
    _Pragma("unroll")                                                          \
    for (int ks = 0; ks < 2; ++ks) {                                           \
      const int kof = ks * 32 + lg * 8;                                        \
      u16x8 av[4], bv[4];                                                      \
      _Pragma("unroll")                                                        \
      for (int m = 0; m < 4; ++m) av[m] = *(const u16x8*)&pa[(wm + m * 16 + lr) * 64 + kof]; \
      _Pragma("unroll")                                                        \
      for (int n = 0; n < 4; ++n) bv[n] = *(const u16x8*)&pb[(wn + n * 16 + lr) * 64 + kof]; \
      _Pragma("unroll")                                                        \
      for (int m = 0; m < 4; ++m)                                              \
        _Pragma("unroll")                                                      \
        for (int n = 0; n < 4; ++n)                                            \
          acc[m][n] = mfma_bf16(av[m], bv[n], acc[m][n]);                      \
    }                                                                          \
  };                                                                           \
  const int nk = Ks >> 6;                                                      \
  loadA(kbase); loadB(kbase);                                                  \
  writeAB(0);                                                                  \
  __syncthreads();                                                             \
  for (int t = 0; t < nk; ++t) {                                               \
    const int cur = t & 1;                                                     \
    if (t + 1 < nk) { loadA(kbase + ((t + 1) << 6)); loadB(kbase + ((t + 1) << 6)); } \
    compute(cur);                                                              \
    if (t + 1 < nk) { writeAB(cur ^ 1); }                                      \
    __syncthreads();                                                           \
  }

// ---------------- GEMM -> fp32 C (fused q_a+kv_a, w_o) ----------------
__global__ __launch_bounds__(256, 2) void gemm_ff(
    const u16* __restrict__ A, const u16* __restrict__ B, float* __restrict__ C,
    int M, int N, int Ks, int lda, int ldb, int ldc)
{
  C += (size_t)blockIdx.y * M * ldc;
  GEMM_PROLOGUE()
#pragma unroll
  for (int m = 0; m < 4; ++m) {
    const int row0 = bm + wm + m * 16 + (lg << 2);
#pragma unroll
    for (int n = 0; n < 4; ++n) {
      const int col = bn + wn + n * 16 + lr;
      if (col < N) {
#pragma unroll
        for (int r = 0; r < 4; ++r)
          C[(size_t)(row0 + r) * ldc + col] = acc[m][n][r];
      }
    }
  }
}

// ---------------- GEMM -> bf16 C (q_b) ----------------
__global__ __launch_bounds__(256, 2) void gemm_fb(
    const u16* __restrict__ A, const u16* __restrict__ B, u16* __restrict__ C,
    int M, int N, int Ks, int lda, int ldb, int ldc)
{
  GEMM_PROLOGUE()
#pragma unroll
  for (int m = 0; m < 4; ++m) {
    const int row0 = bm + wm + m * 16 + (lg << 2);
#pragma unroll
    for (int n = 0; n < 4; ++n) {
      const int col = bn + wn + n * 16 + lr;
#pragma unroll
      for (int r = 0; r < 4; ++r)
        C[(size_t)(row0 + r) * ldc + col] = f2bf(acc[m][n][r]);
    }
  }
}

// ---------------- kv_b GEMM with fused split+transpose epilogue ----------------
// C[s][h*256+c]: c<128 -> Knope[(h*2048+s)*128+c]; c>=128 -> Vt[(h*128+c-128)*2048+s].
__global__ __launch_bounds__(256, 2) void gemm_kvb(
    const u16* __restrict__ A, const u16* __restrict__ B,
    u16* __restrict__ Knope, u16* __restrict__ Vt,
    int M, int N, int Ks, int lda, int ldb)
{
  GEMM_PROLOGUE()
#pragma unroll
  for (int m = 0; m < 4; ++m) {
    const int row0 = bm + wm + m * 16 + (lg << 2);
#pragma unroll
    for (int n = 0; n < 4; ++n) {
      const int col = bn + wn + n * 16 + lr;
      const int h = col >> 8, c = col & 255;
      if (c < 128) {
#pragma unroll
        for (int r = 0; r < 4; ++r)
          Knope[((size_t)h * 2048 + row0 + r) * 128 + c] = f2bf(acc[m][n][r]);
      } else {
        u16x4 v;
        v[0] = f2bf(acc[m][n][0]); v[1] = f2bf(acc[m][n][1]);
        v[2] = f2bf(acc[m][n][2]); v[3] = f2bf(acc[m][n][3]);
        *(u16x4*)&Vt[((size_t)h * 128 + (c - 128)) * 2048 + row0] = v;
      }
    }
  }
}

// ---------------- merged norm epilogues over the fused a-proj partials (R14-verified) ----------------
// blocks [0,2048): RMS over cols 0..1535 -> qlatn (bf16)
// blocks [2048,4096): RMS(512) + rope(64) over cols 1536..2111 -> klatn, krot
__global__ __launch_bounds__(256) void norm_fused(
    const float* __restrict__ qkv_part,
    const float* __restrict__ q_a_ln, const float* __restrict__ kv_a_ln,
    const float* __restrict__ cosp, const float* __restrict__ sinp,
    u16* __restrict__ qlatn, u16* __restrict__ klatn, u16* __restrict__ krot)
{
  const size_t PSTRIDE = (size_t)S_LEN * 2112;
  __shared__ float sb[4];
  if (blockIdx.x < 2048) {
    const int row = blockIdx.x;
    const float* x = qkv_part + (size_t)row * 2112;
    float ss = 0.f;
    for (int i = threadIdx.x * 4; i < 1536; i += 1024) {
      f32x4 v = *(const f32x4*)&x[i];
      f32x4 v2 = *(const f32x4*)&x[PSTRIDE + i];
      v[0] += v2[0]; v[1] += v2[1]; v[2] += v2[2]; v[3] += v2[3];
      ss += v[0] * v[0] + v[1] * v[1] + v[2] * v[2] + v[3] * v[3];
    }
#pragma unroll
    for (int off = 32; off >= 1; off >>= 1) ss += __shfl_xor(ss, off, 64);
    if ((threadIdx.x & 63) == 0) sb[threadIdx.x >> 6] = ss;
    __syncthreads();
    const float inv = rsqrtf((sb[0] + sb[1] + sb[2] + sb[3]) / 1536.0f + 1e-6f);
    u16* o = qlatn + (size_t)row * 1536;
    for (int i = threadIdx.x * 4; i < 1536; i += 1024) {
      f32x4 v = *(const f32x4*)&x[i];
      f32x4 v2 = *(const f32x4*)&x[PSTRIDE + i];
      v[0] += v2[0]; v[1] += v2[1]; v[2] += v2[2]; v[3] += v2[3];
      f32x4 wv = *(const f32x4*)&q_a_ln[i];
      u16x4 u;
      u[0] = f2bf(v[0] * inv * wv[0]); u[1] = f2bf(v[1] * inv * wv[1]);
      u[2] = f2bf(v[2] * inv * wv[2]); u[3] = f2bf(v[3] * inv * wv[3]);
      *(u16x4*)&o[i] = u;
    }
  } else {
    const int s = blockIdx.x - 2048;
    const float* x = qkv_part + 1536 + (size_t)s * 2112;
    const int i2 = threadIdx.x * 2;
    float a = x[i2] + x[PSTRIDE + i2];
    float b = x[i2 + 1] + x[PSTRIDE + i2 + 1];
    float ss = a * a + b * b;
#pragma unroll
    for (int off = 32; off >= 1; off >>= 1) ss += __shfl_xor(ss, off, 64);
    if ((threadIdx.x & 63) == 0) sb[threadIdx.x >> 6] = ss;
    __syncthreads();
    const float inv = rsqrtf((sb[0] + sb[1] + sb[2] + sb[3]) / 512.0f + 1e-6f);
    klatn[(size_t)s * 512 + i2]     = f2bf(a * inv * kv_a_ln[i2]);
    klatn[(size_t)s * 512 + i2 + 1] = f2bf(b * inv * kv_a_ln[i2 + 1]);
    if (threadIdx.x < 64) {
      const int d = threadIdx.x;
      const float xr = x[512 + d] + x[PSTRIDE + 512 + d];
      const int dp = (d < 32) ? (d + 32) : (d - 32);
      const float rrabs = x[512 + dp] + x[PSTRIDE + 512 + dp];
      const float rr = (d < 32) ? -rrabs : rrabs;
      krot[(size_t)s * 64 + d] = f2bf(xr * cosp[s * 64 + d] + rr * sinp[s * 64 + d]);
    }
  }
}

// ---------------- q epilogue (bf16 in): rope + scale + [rope|nope] layout, bf16 ----------------
__global__ __launch_bounds__(256) void q_epi_kernel(const u16* __restrict__ q_raw,
    const float* __restrict__ cosp, const float* __restrict__ sinp, u16* __restrict__ Qb) {
  const int s = blockIdx.x;
  const u16* x = q_raw + (size_t)s * 6144;
  for (int idx = threadIdx.x; idx < 6144; idx += 256) {
    const int h = idx / 192, d = idx - h * 192;
    float v;
    if (d < 64) {
      const float xr = bf2f(x[h * 192 + 128 + d]);
      const float rr = (d < 32) ? -bf2f(x[h * 192 + 160 + d]) : bf2f(x[h * 192 + 96 + d]);
      v = xr * cosp[s * 64 + d] + rr * sinp[s * 64 + d];
    } else {
      v = bf2f(x[h * 192 + d - 64]);
    }
    Qb[((size_t)h * 2048 + s) * QHD + d] = f2bf(v * SCALING_F);
  }
}

// ---------------- flash attention (causal), 4 waves, QBLK=128, KVBLK=64 ----------------
// EXACT R1/R8/R12 structure (measured 244us / 40MB fetch): linear LDS, natural
// block order, no setprio, no barrier. DO NOT MODIFY — fragile cache-lockstep regime.
__global__ __launch_bounds__(256, 2) void flash_kernel(
    const u16* __restrict__ Qb, const u16* __restrict__ Krot,
    const u16* __restrict__ Knope, const u16* __restrict__ Vt,
    u16* __restrict__ attnb)
{
  const int h = blockIdx.x & 31, qt = blockIdx.x >> 5;
  const int q0 = qt << 7;
  __shared__ u16 sK[64][QHD];      // [kv][rope(64)|nope(128)]
  __shared__ u16 sV[VDIM][64];     // V^T [d][kv]
  __shared__ u16 sP[4][32][64];    // per-wave P
  const int tid = threadIdx.x;
  const int wid = tid >> 6, lane = tid & 63;
  const int lr = lane & 15, lg = lane >> 4;

  u16x8 qf[2][6];
#pragma unroll
  for (int m = 0; m < 2; ++m) {
    const int row = q0 + wid * 32 + m * 16 + lr;
#pragma unroll
    for (int kk = 0; kk < 6; ++kk)
      qf[m][kk] = *(const u16x8*)&Qb[((size_t)h * 2048 + row) * QHD + kk * 32 + lg * 8];
  }

  f32x4 acc[2][8] = {};
  float mx[2][4], ls[2][4];
#pragma unroll
  for (int m = 0; m < 2; ++m)
#pragma unroll
    for (int r = 0; r < 4; ++r) { mx[m][r] = -1e30f; ls[m][r] = 0.f; }

  const int nkv = q0 + 128;
  u16x8 kreg[6], vreg[4];

  auto loadKV = [&](int kv0) {
#pragma unroll
    for (int i = 0; i < 6; ++i) {
      const int chunk = i * 256 + tid;
      const int row = chunk / 24, cc = chunk % 24;
      const u16* src = (cc < 8)
          ? &Krot[(size_t)(kv0 + row) * 64 + cc * 8]
          : &Knope[((size_t)h * 2048 + kv0 + row) * 128 + (cc - 8) * 8];
      kreg[i] = *(const u16x8*)src;
    }
#pragma unroll
    for (int i = 0; i < 4; ++i) {
      const int chunk = i * 256 + tid;
      const int d = chunk >> 3, c = chunk & 7;
      vreg[i] = *(const u16x8*)&Vt[((size_t)h * VDIM + d) * 2048 + kv0 + c * 8];
    }
  };

  loadKV(0);
  for (int kv0 = 0; kv0 < nkv; kv0 += 64) {
    __syncthreads();  // prior compute done before overwriting sK/sV
    u16* kbase = &sK[0][0];
#pragma unroll
    for (int i = 0; i < 6; ++i) *(u16x8*)&kbase[(size_t)(i * 256 + tid) * 8] = kreg[i];
    u16* vbase = &sV[0][0];
#pragma unroll
    for (int i = 0; i < 4; ++i) *(u16x8*)&vbase[(size_t)(i * 256 + tid) * 8] = vreg[i];
    __syncthreads();
    if (kv0 + 64 < nkv) loadKV(kv0 + 64);  // prefetch overlaps compute

    // S^ = Q K^T  (per wave: 32 q rows x 64 kv)
    f32x4 sc[2][4] = {};
#pragma unroll
    for (int kk = 0; kk < 6; ++kk) {
      u16x8 bfr[4];
#pragma unroll
      for (int n = 0; n < 4; ++n) bfr[n] = *(const u16x8*)&sK[n * 16 + lr][kk * 32 + lg * 8];
#pragma unroll
      for (int m = 0; m < 2; ++m)
#pragma unroll
        for (int n = 0; n < 4; ++n)
          sc[m][n] = mfma_bf16(qf[m][kk], bfr[n], sc[m][n]);
    }

    // causal mask
    if (kv0 + 63 > q0 + wid * 32) {
#pragma unroll
      for (int m = 0; m < 2; ++m)
#pragma unroll
        for (int n = 0; n < 4; ++n) {
          const int kv = kv0 + n * 16 + lr;
#pragma unroll
          for (int r = 0; r < 4; ++r) {
            const int rowq = q0 + wid * 32 + m * 16 + lg * 4 + r;
            if (kv > rowq) sc[m][n][r] = -1e30f;
          }
        }
    }

    // online softmax (rows live in (lg, reg); reduce across lr lanes)
#pragma unroll
    for (int m = 0; m < 2; ++m) {
      float rs[4];
#pragma unroll
      for (int r = 0; r < 4; ++r) {
        float v = fmaxf(fmaxf(sc[m][0][r], sc[m][1][r]), fmaxf(sc[m][2][r], sc[m][3][r]));
#pragma unroll
        for (int off = 1; off < 16; off <<= 1) v = fmaxf(v, __shfl_xor(v, off, 64));
        const float mnew = fmaxf(mx[m][r], v);
        const float alpha = __expf(mx[m][r] - mnew);
        mx[m][r] = mnew;
        ls[m][r] *= alpha;
#pragma unroll
        for (int df = 0; df < 8; ++df) acc[m][df][r] *= alpha;
        rs[r] = 0.f;
      }
#pragma unroll
      for (int n = 0; n < 4; ++n)
#pragma unroll
        for (int r = 0; r < 4; ++r) {
          const float p = __expf(sc[m][n][r] - mx[m][r]);
          rs[r] += p;
          sP[wid][m * 16 + lg * 4 + r][n * 16 + lr] = f2bf(p);
        }
#pragma unroll
      for (int r = 0; r < 4; ++r) {
        float v = rs[r];
#pragma unroll
        for (int off = 1; off < 16; off <<= 1) v += __shfl_xor(v, off, 64);
        ls[m][r] += v;
      }
    }

    // PV: acc += P * V
#pragma unroll
    for (int ks = 0; ks < 2; ++ks) {
      u16x8 pf0 = *(const u16x8*)&sP[wid][lr][ks * 32 + lg * 8];
      u16x8 pf1 = *(const u16x8*)&sP[wid][16 + lr][ks * 32 + lg * 8];
#pragma unroll
      for (int df = 0; df < 8; ++df) {
        u16x8 vf = *(const u16x8*)&sV[df * 16 + lr][ks * 32 + lg * 8];
        acc[0][df] = mfma_bf16(pf0, vf, acc[0][df]);
        acc[1][df] = mfma_bf16(pf1, vf, acc[1][df]);
      }
    }
  }

  // epilogue: attn(s, h*128+d) bf16
#pragma unroll
  for (int m = 0; m < 2; ++m)
#pragma unroll
    for (int df = 0; df < 8; ++df) {
      const int col = h * 128 + df * 16 + lr;
#pragma unroll
      for (int r = 0; r < 4; ++r) {
        const int row = q0 + wid * 32 + m * 16 + lg * 4 + r;
        attnb[(size_t)row * 4096 + col] = f2bf(acc[m][df][r] / ls[m][r]);
      }
    }
}

extern "C" void kernel_launch(void* const* d_in, const int* in_sizes, int n_in,
                              void* d_out, int out_size, void* d_ws, size_t ws_size,
                              hipStream_t stream) {
  (void)in_sizes; (void)n_in; (void)out_size; (void)ws_size;
  const float* hidden  = (const float*)d_in[0];
  const float* cosp    = (const float*)d_in[1];
  const float* sinp    = (const float*)d_in[2];
  const float* w_q_a   = (const float*)d_in[3];
  const float* q_a_ln  = (const float*)d_in[4];
  const float* w_q_b   = (const float*)d_in[5];
  const float* w_kv_a  = (const float*)d_in[6];
  const float* kv_a_ln = (const float*)d_in[7];
  const float* w_kv_b  = (const float*)d_in[8];
  const float* w_o     = (const float*)d_in[9];
  float* out = (float*)d_out;

  char* p = (char*)d_ws;
  auto alloc = [&](size_t bytes) { char* r = p; p += (bytes + 255) & ~(size_t)255; return r; };
  u16* Hb      = (u16*)alloc((size_t)S_LEN * HIDDEN_D * 2);
  u16* qlatn   = (u16*)alloc((size_t)S_LEN * QLORA * 2);
  u16* klatn   = (u16*)alloc((size_t)S_LEN * KVLORA * 2);
  u16* krot    = (u16*)alloc((size_t)S_LEN * ROPED * 2);
  u16* Qb      = (u16*)alloc((size_t)NHEADS * S_LEN * QHD * 2);
  u16* Knope   = (u16*)alloc((size_t)NHEADS * S_LEN * NOPED * 2);
  u16* Vt      = (u16*)alloc((size_t)NHEADS * VDIM * S_LEN * 2);
  u16* attnb   = (u16*)alloc((size_t)S_LEN * 4096 * 2);
  u16* WqaKva  = (u16*)alloc((size_t)2112 * HIDDEN_D * 2);   // [w_q_a(1536); w_kv_a(576)]
  u16* Wqb     = (u16*)alloc((size_t)6144 * QLORA * 2);
  u16* Wkvb    = (u16*)alloc((size_t)8192 * KVLORA * 2);
  u16* Wo      = (u16*)alloc((size_t)HIDDEN_D * 4096 * 2);
  u16* qraw16  = (u16*)alloc((size_t)S_LEN * 6144 * 2);
  float* qkv_part = (float*)alloc((size_t)2 * S_LEN * 2112 * 4);  // 2 split-K partials

  // 1. fused converts (hidden + 4 weights) + w_q_b convert
  cvt_all<<<37120, 256, 0, stream>>>(hidden, Hb, w_q_a, w_kv_a, WqaKva, w_kv_b, Wkvb, w_o, Wo);
  cvt_kernel<<<(6144 * QLORA / 4 + 255) / 256, 256, 0, stream>>>(w_q_b, Wqb, 6144 * QLORA / 4);
  // 2. fused [q_lat | ckv] partials = Hb @ WqaKva^T  (2048 x 2112, K=4096 split 2)
  gemm_ff<<<dim3(16 * 17, 2), 256, 0, stream>>>(Hb, WqaKva, qkv_part, 2048, 2112, 2048, 4096, 4096, 2112);
  // 3. merged RMS(q_lat) + RMS/rope(ckv) epilogues
  norm_fused<<<4096, 256, 0, stream>>>(qkv_part, q_a_ln, kv_a_ln, cosp, sinp, qlatn, klatn, krot);
  // 4. q = qlatn @ Wqb^T  (2048 x 6144, K=1536, bf16 out)
  gemm_fb<<<dim3(16 * 48, 1), 256, 0, stream>>>(qlatn, Wqb, qraw16, 2048, 6144, 1536, 1536, 1536, 6144);
  // 5. rope+scale+layout -> Qb
  q_epi_kernel<<<2048, 256, 0, stream>>>(qraw16, cosp, sinp, Qb);
  // 6. kv = klatn @ Wkvb^T with fused split+transpose -> Knope, Vt (bf16)
  gemm_kvb<<<dim3(16 * 64, 1), 256, 0, stream>>>(klatn, Wkvb, Knope, Vt, 2048, 8192, 512, 512, 512);
  // 7. causal flash attention (exact R8/R12 known-good structure)
  flash_kernel<<<512, 256, 0, stream>>>(Qb, krot, Knope, Vt, attnb);
  // 8. out = attn @ Wo^T  (2048 x 4096, K=4096, fp32 out)
  gemm_ff<<<dim3(16 * 32, 1), 256, 0, stream>>>(attnb, Wo, out, 2048, 4096, 4096, 4096, 4096, 4096);
}

// Round 18
// 567.336 us; speedup vs baseline: 1.0733x; 1.0329x over previous
//
#include <hip/hip_runtime.h>

typedef unsigned short u16;
typedef u16 u16x4 __attribute__((ext_vector_type(4)));
typedef u16 u16x8 __attribute__((ext_vector_type(8)));
typedef float f32x4 __attribute__((ext_vector_type(4)));
typedef __bf16 bf16x8 __attribute__((ext_vector_type(8)));

#define S_LEN 2048
#define HIDDEN_D 4096
#define NHEADS 32
#define QLORA 1536
#define KVLORA 512
#define ROPED 64
#define NOPED 128
#define VDIM 128
#define QHD 192
#define SCALING_F 0.07216878364870323f

__device__ __forceinline__ u16 f2bf(float x) {
  union { float f; unsigned u; } v; v.f = x;
  unsigned r = v.u + 0x7fffu + ((v.u >> 16) & 1u);
  return (u16)(r >> 16);
}
__device__ __forceinline__ float bf2f(u16 x) {
  union { unsigned u; float f; } v; v.u = ((unsigned)x) << 16; return v.f;
}

__device__ __forceinline__ f32x4 mfma_bf16(u16x8 a, u16x8 b, f32x4 c) {
  return __builtin_amdgcn_mfma_f32_16x16x32_bf16(
      __builtin_bit_cast(bf16x8, a), __builtin_bit_cast(bf16x8, b), c, 0, 0, 0);
}

// ---------------- fused fp32->bf16 convert for 5 linear tensors (R14/R17-verified) ----------------
// segments (blocks): [0,8192) hidden; [8192,14336) w_q_a; [14336,16640) w_kv_a;
// [16640,20736) w_kv_b; [20736,37120) w_o.  All sizes exact multiples of 1024 elems.
__global__ __launch_bounds__(256) void cvt_all(
    const float* __restrict__ hsrc, u16* __restrict__ Hb,
    const float* __restrict__ wqa, const float* __restrict__ wkva, u16* __restrict__ WqaKva,
    const float* __restrict__ wkvb, u16* __restrict__ Wkvb,
    const float* __restrict__ wo, u16* __restrict__ Wo)
{
  const int b = blockIdx.x, t = threadIdx.x;
  const float* src; u16* dst; size_t idx;
  if (b < 8192)       { src = hsrc; dst = Hb;     idx = (size_t)b * 256 + t; }
  else if (b < 14336) { src = wqa;  dst = WqaKva; idx = (size_t)(b - 8192) * 256 + t; }
  else if (b < 16640) { src = wkva; dst = WqaKva + (size_t)QLORA * HIDDEN_D; idx = (size_t)(b - 14336) * 256 + t; }
  else if (b < 20736) { src = wkvb; dst = Wkvb;   idx = (size_t)(b - 16640) * 256 + t; }
  else                { src = wo;   dst = Wo;     idx = (size_t)(b - 20736) * 256 + t; }
  f32x4 v = ((const f32x4*)src)[idx];
  u16x4 o;
  o[0] = f2bf(v[0]); o[1] = f2bf(v[1]); o[2] = f2bf(v[2]); o[3] = f2bf(v[3]);
  ((u16x4*)dst)[idx] = o;
}

// ---------------- plain fp32 -> bf16 convert (w_q_b) ----------------
__global__ __launch_bounds__(256) void cvt_kernel(const float* __restrict__ in,
                                                  u16* __restrict__ out, int n4) {
  int i = blockIdx.x * 256 + threadIdx.x;
  if (i >= n4) return;
  f32x4 v = ((const f32x4*)in)[i];
  u16x4 o;
  o[0] = f2bf(v[0]); o[1] = f2bf(v[1]); o[2] = f2bf(v[2]); o[3] = f2bf(v[3]);
  ((u16x4*)out)[i] = o;
}

// ============ GEMM core (R9-proven): A bf16 * B bf16^T, reg-staged dbuf LDS ============

#define GEMM_PROLOGUE()                                                        \
  __shared__ u16 sA[2][128 * 64];                                              \
  __shared__ u16 sB[2][128 * 64];                                              \
  const int tid = threadIdx.x;                                                 \
  const int wid = tid >> 6, lane = tid & 63;                                   \
  const int lr = lane & 15, lg = lane >> 4;                                    \
  const int nbn = (N + 127) >> 7;                                              \
  const int bx = blockIdx.x % nbn, by = blockIdx.x / nbn;                      \
  const int bm = by << 7, bn = bx << 7;                                        \
  const int wm = (wid >> 1) << 6, wn = (wid & 1) << 6;                         \
  const int kbase = blockIdx.y * Ks;                                           \
  f32x4 acc[4][4] = {};                                                        \
  u16x8 areg[4], breg[4];                                                      \
  auto loadA = [&](int k0) {                                                   \
    _Pragma("unroll")                                                          \
    for (int i = 0; i < 4; ++i) {                                              \
      int chunk = i * 256 + tid;                                               \
      int row = chunk >> 3, c8 = chunk & 7;                                    \
      int gr = bm + row; if (gr >= M) gr = M - 1;                              \
      areg[i] = *(const u16x8*)(A + (size_t)gr * lda + k0 + (c8 << 3));        \
    }                                                                          \
  };                                                                           \
  auto loadB = [&](int k0) {                                                   \
    _Pragma("unroll")                                                          \
    for (int i = 0; i < 4; ++i) {                                              \
      int chunk = i * 256 + tid;                                               \
      int n = chunk >> 3, c8 = chunk & 7;                                      \
      int gn = bn + n; if (gn >= N) gn = N - 1;                                \
      breg[i] = *(const u16x8*)(B + (size_t)gn * ldb + k0 + (c8 << 3));        \
    }                                                                          \
  };                                                                           \
  auto writeAB = [&](int buf) {                                                \
    _Pragma("unroll")                                                          \
    for (int i = 0; i < 4; ++i) {                                              \
      *(u16x8*)&sA[buf][(i * 256 + tid) * 8] = areg[i];                        \
      *(u16x8*)&sB[buf][(i * 256 + tid) * 8] = breg[i];                        \
    }                                                                          \
  };                                                                           \
  auto compute = [&](int buf) {                                                \
    const u16* pa = sA[buf];                                                   \
    const u16* pb = sB[buf];                                                   \
    _Pragma("unroll")                                                          \
    for (int ks = 0; ks < 2; ++ks) {                                           \
      const int kof = ks * 32 + lg * 8;                                        \
      u16x8 av[4], bv[4];                                                      \
      _Pragma("unroll")                                                        \
      for (int m = 0; m < 4; ++m) av[m] = *(const u16x8*)&pa[(wm + m * 16 + lr) * 64 + kof]; \
      _Pragma("unroll")                                                        \
      for (int n = 0; n < 4; ++n) bv[n] = *(const u16x8*)&pb[(wn + n * 16 + lr) * 64 + kof]; \
      _Pragma("unroll")                                                        \
      for (int m = 0; m < 4; ++m)                                              \
        _Pragma("unroll")                                                      \
        for (int n = 0; n < 4; ++n)                                            \
          acc[m][n] = mfma_bf16(av[m], bv[n], acc[m][n]);                      \
    }                                                                          \
  };                                                                           \
  const int nk = Ks >> 6;                                                      \
  loadA(kbase); loadB(kbase);                                                  \
  writeAB(0);                                                                  \
  __syncthreads();                                                             \
  for (int t = 0; t < nk; ++t) {                                               \
    const int cur = t & 1;                                                     \
    if (t + 1 < nk) { loadA(kbase + ((t + 1) << 6)); loadB(kbase + ((t + 1) << 6)); } \
    compute(cur);                                                              \
    if (t + 1 < nk) { writeAB(cur ^ 1); }                                      \
    __syncthreads();                                                           \
  }

// ---------------- GEMM -> fp32 C (fused q_a+kv_a, w_o) ----------------
__global__ __launch_bounds__(256, 2) void gemm_ff(
    const u16* __restrict__ A, const u16* __restrict__ B, float* __restrict__ C,
    int M, int N, int Ks, int lda, int ldb, int ldc)
{
  C += (size_t)blockIdx.y * M * ldc;
  GEMM_PROLOGUE()
#pragma unroll
  for (int m = 0; m < 4; ++m) {
    const int row0 = bm + wm + m * 16 + (lg << 2);
#pragma unroll
    for (int n = 0; n < 4; ++n) {
      const int col = bn + wn + n * 16 + lr;
      if (col < N) {
#pragma unroll
        for (int r = 0; r < 4; ++r)
          C[(size_t)(row0 + r) * ldc + col] = acc[m][n][r];
      }
    }
  }
}

// ---------------- q_b GEMM with fused rope+scale+layout epilogue -> Qb ----------------
// Wave tile spans 64 cols; 192%64==0 so base%192 in {0,64,128} is wave-uniform:
//   0/64  -> pure nope third: Qb[h][s][tc+64] = acc*scale
//   128   -> pure rope third: x slots n in {0,1} (tc-128 in [0,32)), y partner at acc[m][n+2];
//            Qb[h][s][dx]    = (x*cos[dx]    - y*sin[dx])   *scale
//            Qb[h][s][dx+32] = (y*cos[dx+32] + x*sin[dx+32])*scale
__global__ __launch_bounds__(256, 2) void gemm_qb(
    const u16* __restrict__ A, const u16* __restrict__ B,
    const float* __restrict__ cosp, const float* __restrict__ sinp,
    u16* __restrict__ Qb, int M, int N, int Ks, int lda, int ldb)
{
  GEMM_PROLOGUE()
  const int base = bn + wn;          // multiple of 64, wave-uniform
  const int h = base / 192;
  const int ht = base - h * 192;     // 0, 64, or 128
  if (ht < 128) {
    // nope third: tc = ht + n*16 + lr, output d = tc + 64
#pragma unroll
    for (int m = 0; m < 4; ++m) {
      const int row0 = bm + wm + m * 16 + (lg << 2);
#pragma unroll
      for (int n = 0; n < 4; ++n) {
        const int d = ht + n * 16 + lr + 64;
#pragma unroll
        for (int r = 0; r < 4; ++r)
          Qb[((size_t)h * 2048 + row0 + r) * QHD + d] = f2bf(acc[m][n][r] * SCALING_F);
      }
    }
  } else {
    // rope third: x at n in {0,1}, y at n+2
#pragma unroll
    for (int m = 0; m < 4; ++m) {
      const int row0 = bm + wm + m * 16 + (lg << 2);
#pragma unroll
      for (int n = 0; n < 2; ++n) {
        const int dx = n * 16 + lr;        // [0,32)
#pragma unroll
        for (int r = 0; r < 4; ++r) {
          const int s = row0 + r;
          const float cx = cosp[s * 64 + dx],      sx = sinp[s * 64 + dx];
          const float cy = cosp[s * 64 + dx + 32], sy = sinp[s * 64 + dx + 32];
          const float xv = acc[m][n][r], yv = acc[m][n + 2][r];
          Qb[((size_t)h * 2048 + s) * QHD + dx]      = f2bf((xv * cx - yv * sx) * SCALING_F);
          Qb[((size_t)h * 2048 + s) * QHD + dx + 32] = f2bf((yv * cy + xv * sy) * SCALING_F);
        }
      }
    }
  }
}

// ---------------- kv_b GEMM with fused split+transpose epilogue ----------------
// C[s][h*256+c]: c<128 -> Knope[(h*2048+s)*128+c]; c>=128 -> Vt[(h*128+c-128)*2048+s].
__global__ __launch_bounds__(256, 2) void gemm_kvb(
    const u16* __restrict__ A, const u16* __restrict__ B,
    u16* __restrict__ Knope, u16* __restrict__ Vt,
    int M, int N, int Ks, int lda, int ldb)
{
  GEMM_PROLOGUE()
#pragma unroll
  for (int m = 0; m < 4; ++m) {
    const int row0 = bm + wm + m * 16 + (lg << 2);
#pragma unroll
    for (int n = 0; n < 4; ++n) {
      const int col = bn + wn + n * 16 + lr;
      const int h = col >> 8, c = col & 255;
      if (c < 128) {
#pragma unroll
        for (int r = 0; r < 4; ++r)
          Knope[((size_t)h * 2048 + row0 + r) * 128 + c] = f2bf(acc[m][n][r]);
      } else {
        u16x4 v;
        v[0] = f2bf(acc[m][n][0]); v[1] = f2bf(acc[m][n][1]);
        v[2] = f2bf(acc[m][n][2]); v[3] = f2bf(acc[m][n][3]);
        *(u16x4*)&Vt[((size_t)h * 128 + (c - 128)) * 2048 + row0] = v;
      }
    }
  }
}

// ---------------- merged norm epilogues over the fused a-proj partials (R14/R17-verified) ----------------
// blocks [0,2048): RMS over cols 0..1535 -> qlatn (bf16)
// blocks [2048,4096): RMS(512) + rope(64) over cols 1536..2111 -> klatn, krot
__global__ __launch_bounds__(256) void norm_fused(
    const float* __restrict__ qkv_part,
    const float* __restrict__ q_a_ln, const float* __restrict__ kv_a_ln,
    const float* __restrict__ cosp, const float* __restrict__ sinp,
    u16* __restrict__ qlatn, u16* __restrict__ klatn, u16* __restrict__ krot)
{
  const size_t PSTRIDE = (size_t)S_LEN * 2112;
  __shared__ float sb[4];
  if (blockIdx.x < 2048) {
    const int row = blockIdx.x;
    const float* x = qkv_part + (size_t)row * 2112;
    float ss = 0.f;
    for (int i = threadIdx.x * 4; i < 1536; i += 1024) {
      f32x4 v = *(const f32x4*)&x[i];
      f32x4 v2 = *(const f32x4*)&x[PSTRIDE + i];
      v[0] += v2[0]; v[1] += v2[1]; v[2] += v2[2]; v[3] += v2[3];
      ss += v[0] * v[0] + v[1] * v[1] + v[2] * v[2] + v[3] * v[3];
    }
#pragma unroll
    for (int off = 32; off >= 1; off >>= 1) ss += __shfl_xor(ss, off, 64);
    if ((threadIdx.x & 63) == 0) sb[threadIdx.x >> 6] = ss;
    __syncthreads();
    const float inv = rsqrtf((sb[0] + sb[1] + sb[2] + sb[3]) / 1536.0f + 1e-6f);
    u16* o = qlatn + (size_t)row * 1536;
    for (int i = threadIdx.x * 4; i < 1536; i += 1024) {
      f32x4 v = *(const f32x4*)&x[i];
      f32x4 v2 = *(const f32x4*)&x[PSTRIDE + i];
      v[0] += v2[0]; v[1] += v2[1]; v[2] += v2[2]; v[3] += v2[3];
      f32x4 wv = *(const f32x4*)&q_a_ln[i];
      u16x4 u;
      u[0] = f2bf(v[0] * inv * wv[0]); u[1] = f2bf(v[1] * inv * wv[1]);
      u[2] = f2bf(v[2] * inv * wv[2]); u[3] = f2bf(v[3] * inv * wv[3]);
      *(u16x4*)&o[i] = u;
    }
  } else {
    const int s = blockIdx.x - 2048;
    const float* x = qkv_part + 1536 + (size_t)s * 2112;
    const int i2 = threadIdx.x * 2;
    float a = x[i2] + x[PSTRIDE + i2];
    float b = x[i2 + 1] + x[PSTRIDE + i2 + 1];
    float ss = a * a + b * b;
#pragma unroll
    for (int off = 32; off >= 1; off >>= 1) ss += __shfl_xor(ss, off, 64);
    if ((threadIdx.x & 63) == 0) sb[threadIdx.x >> 6] = ss;
    __syncthreads();
    const float inv = rsqrtf((sb[0] + sb[1] + sb[2] + sb[3]) / 512.0f + 1e-6f);
    klatn[(size_t)s * 512 + i2]     = f2bf(a * inv * kv_a_ln[i2]);
    klatn[(size_t)s * 512 + i2 + 1] = f2bf(b * inv * kv_a_ln[i2 + 1]);
    if (threadIdx.x < 64) {
      const int d = threadIdx.x;
      const float xr = x[512 + d] + x[PSTRIDE + 512 + d];
      const int dp = (d < 32) ? (d + 32) : (d - 32);
      const float rrabs = x[512 + dp] + x[PSTRIDE + 512 + dp];
      const float rr = (d < 32) ? -rrabs : rrabs;
      krot[(size_t)s * 64 + d] = f2bf(xr * cosp[s * 64 + d] + rr * sinp[s * 64 + d]);
    }
  }
}

// ---------------- flash attention (causal), 4 waves, QBLK=128, KVBLK=64 ----------------
// EXACT R1/R8/R12 structure (measured 244us / 40MB fetch): linear LDS, natural
// block order, no setprio, no barrier. DO NOT MODIFY — fragile cache-lockstep regime.
__global__ __launch_bounds__(256, 2) void flash_kernel(
    const u16* __restrict__ Qb, const u16* __restrict__ Krot,
    const u16* __restrict__ Knope, const u16* __restrict__ Vt,
    u16* __restrict__ attnb)
{
  const int h = blockIdx.x & 31, qt = blockIdx.x >> 5;
  const int q0 = qt << 7;
  __shared__ u16 sK[64][QHD];      // [kv][rope(64)|nope(128)]
  __shared__ u16 sV[VDIM][64];     // V^T [d][kv]
  __shared__ u16 sP[4][32][64];    // per-wave P
  const int tid = threadIdx.x;
  const int wid = tid >> 6, lane = tid & 63;
  const int lr = lane & 15, lg = lane >> 4;

  u16x8 qf[2][6];
#pragma unroll
  for (int m = 0; m < 2; ++m) {
    const int row = q0 + wid * 32 + m * 16 + lr;
#pragma unroll
    for (int kk = 0; kk < 6; ++kk)
      qf[m][kk] = *(const u16x8*)&Qb[((size_t)h * 2048 + row) * QHD + kk * 32 + lg * 8];
  }

  f32x4 acc[2][8] = {};
  float mx[2][4], ls[2][4];
#pragma unroll
  for (int m = 0; m < 2; ++m)
#pragma unroll
    for (int r = 0; r < 4; ++r) { mx[m][r] = -1e30f; ls[m][r] = 0.f; }

  const int nkv = q0 + 128;
  u16x8 kreg[6], vreg[4];

  auto loadKV = [&](int kv0) {
#pragma unroll
    for (int i = 0; i < 6; ++i) {
      const int chunk = i * 256 + tid;
      const int row = chunk / 24, cc = chunk % 24;
      const u16* src = (cc < 8)
          ? &Krot[(size_t)(kv0 + row) * 64 + cc * 8]
          : &Knope[((size_t)h * 2048 + kv0 + row) * 128 + (cc - 8) * 8];
      kreg[i] = *(const u16x8*)src;
    }
#pragma unroll
    for (int i = 0; i < 4; ++i) {
      const int chunk = i * 256 + tid;
      const int d = chunk >> 3, c = chunk & 7;
      vreg[i] = *(const u16x8*)&Vt[((size_t)h * VDIM + d) * 2048 + kv0 + c * 8];
    }
  };

  loadKV(0);
  for (int kv0 = 0; kv0 < nkv; kv0 += 64) {
    __syncthreads();  // prior compute done before overwriting sK/sV
    u16* kbase = &sK[0][0];
#pragma unroll
    for (int i = 0; i < 6; ++i) *(u16x8*)&kbase[(size_t)(i * 256 + tid) * 8] = kreg[i];
    u16* vbase = &sV[0][0];
#pragma unroll
    for (int i = 0; i < 4; ++i) *(u16x8*)&vbase[(size_t)(i * 256 + tid) * 8] = vreg[i];
    __syncthreads();
    if (kv0 + 64 < nkv) loadKV(kv0 + 64);  // prefetch overlaps compute

    // S^ = Q K^T  (per wave: 32 q rows x 64 kv)
    f32x4 sc[2][4] = {};
#pragma unroll
    for (int kk = 0; kk < 6; ++kk) {
      u16x8 bfr[4];
#pragma unroll
      for (int n = 0; n < 4; ++n) bfr[n] = *(const u16x8*)&sK[n * 16 + lr][kk * 32 + lg * 8];
#pragma unroll
      for (int m = 0; m < 2; ++m)
#pragma unroll
        for (int n = 0; n < 4; ++n)
          sc[m][n] = mfma_bf16(qf[m][kk], bfr[n], sc[m][n]);
    }

    // causal mask
    if (kv0 + 63 > q0 + wid * 32) {
#pragma unroll
      for (int m = 0; m < 2; ++m)
#pragma unroll
        for (int n = 0; n < 4; ++n) {
          const int kv = kv0 + n * 16 + lr;
#pragma unroll
          for (int r = 0; r < 4; ++r) {
            const int rowq = q0 + wid * 32 + m * 16 + lg * 4 + r;
            if (kv > rowq) sc[m][n][r] = -1e30f;
          }
        }
    }

    // online softmax (rows live in (lg, reg); reduce across lr lanes)
#pragma unroll
    for (int m = 0; m < 2; ++m) {
      float rs[4];
#pragma unroll
      for (int r = 0; r < 4; ++r) {
        float v = fmaxf(fmaxf(sc[m][0][r], sc[m][1][r]), fmaxf(sc[m][2][r], sc[m][3][r]));
#pragma unroll
        for (int off = 1; off < 16; off <<= 1) v = fmaxf(v, __shfl_xor(v, off, 64));
        const float mnew = fmaxf(mx[m][r], v);
        const float alpha = __expf(mx[m][r] - mnew);
        mx[m][r] = mnew;
        ls[m][r] *= alpha;
#pragma unroll
        for (int df = 0; df < 8; ++df) acc[m][df][r] *= alpha;
        rs[r] = 0.f;
      }
#pragma unroll
      for (int n = 0; n < 4; ++n)
#pragma unroll
        for (int r = 0; r < 4; ++r) {
          const float p = __expf(sc[m][n][r] - mx[m][r]);
          rs[r] += p;
          sP[wid][m * 16 + lg * 4 + r][n * 16 + lr] = f2bf(p);
        }
#pragma unroll
      for (int r = 0; r < 4; ++r) {
        float v = rs[r];
#pragma unroll
        for (int off = 1; off < 16; off <<= 1) v += __shfl_xor(v, off, 64);
        ls[m][r] += v;
      }
    }

    // PV: acc += P * V
#pragma unroll
    for (int ks = 0; ks < 2; ++ks) {
      u16x8 pf0 = *(const u16x8*)&sP[wid][lr][ks * 32 + lg * 8];
      u16x8 pf1 = *(const u16x8*)&sP[wid][16 + lr][ks * 32 + lg * 8];
#pragma unroll
      for (int df = 0; df < 8; ++df) {
        u16x8 vf = *(const u16x8*)&sV[df * 16 + lr][ks * 32 + lg * 8];
        acc[0][df] = mfma_bf16(pf0, vf, acc[0][df]);
        acc[1][df] = mfma_bf16(pf1, vf, acc[1][df]);
      }
    }
  }

  // epilogue: attn(s, h*128+d) bf16
#pragma unroll
  for (int m = 0; m < 2; ++m)
#pragma unroll
    for (int df = 0; df < 8; ++df) {
      const int col = h * 128 + df * 16 + lr;
#pragma unroll
      for (int r = 0; r < 4; ++r) {
        const int row = q0 + wid * 32 + m * 16 + lg * 4 + r;
        attnb[(size_t)row * 4096 + col] = f2bf(acc[m][df][r] / ls[m][r]);
      }
    }
}

extern "C" void kernel_launch(void* const* d_in, const int* in_sizes, int n_in,
                              void* d_out, int out_size, void* d_ws, size_t ws_size,
                              hipStream_t stream) {
  (void)in_sizes; (void)n_in; (void)out_size; (void)ws_size;
  const float* hidden  = (const float*)d_in[0];
  const float* cosp    = (const float*)d_in[1];
  const float* sinp    = (const float*)d_in[2];
  const float* w_q_a   = (const float*)d_in[3];
  const float* q_a_ln  = (const float*)d_in[4];
  const float* w_q_b   = (const float*)d_in[5];
  const float* w_kv_a  = (const float*)d_in[6];
  const float* kv_a_ln = (const float*)d_in[7];
  const float* w_kv_b  = (const float*)d_in[8];
  const float* w_o     = (const float*)d_in[9];
  float* out = (float*)d_out;

  char* p = (char*)d_ws;
  auto alloc = [&](size_t bytes) { char* r = p; p += (bytes + 255) & ~(size_t)255; return r; };
  u16* Hb      = (u16*)alloc((size_t)S_LEN * HIDDEN_D * 2);
  u16* qlatn   = (u16*)alloc((size_t)S_LEN * QLORA * 2);
  u16* klatn   = (u16*)alloc((size_t)S_LEN * KVLORA * 2);
  u16* krot    = (u16*)alloc((size_t)S_LEN * ROPED * 2);
  u16* Qb      = (u16*)alloc((size_t)NHEADS * S_LEN * QHD * 2);
  u16* Knope   = (u16*)alloc((size_t)NHEADS * S_LEN * NOPED * 2);
  u16* Vt      = (u16*)alloc((size_t)NHEADS * VDIM * S_LEN * 2);
  u16* attnb   = (u16*)alloc((size_t)S_LEN * 4096 * 2);
  u16* WqaKva  = (u16*)alloc((size_t)2112 * HIDDEN_D * 2);   // [w_q_a(1536); w_kv_a(576)]
  u16* Wqb     = (u16*)alloc((size_t)6144 * QLORA * 2);
  u16* Wkvb    = (u16*)alloc((size_t)8192 * KVLORA * 2);
  u16* Wo      = (u16*)alloc((size_t)HIDDEN_D * 4096 * 2);
  float* qkv_part = (float*)alloc((size_t)2 * S_LEN * 2112 * 4);  // 2 split-K partials

  // 1. fused converts (hidden + 4 weights) + w_q_b convert
  cvt_all<<<37120, 256, 0, stream>>>(hidden, Hb, w_q_a, w_kv_a, WqaKva, w_kv_b, Wkvb, w_o, Wo);
  cvt_kernel<<<(6144 * QLORA / 4 + 255) / 256, 256, 0, stream>>>(w_q_b, Wqb, 6144 * QLORA / 4);
  // 2. fused [q_lat | ckv] partials = Hb @ WqaKva^T  (2048 x 2112, K=4096 split 2)
  gemm_ff<<<dim3(16 * 17, 2), 256, 0, stream>>>(Hb, WqaKva, qkv_part, 2048, 2112, 2048, 4096, 4096, 2112);
  // 3. merged RMS(q_lat) + RMS/rope(ckv) epilogues
  norm_fused<<<4096, 256, 0, stream>>>(qkv_part, q_a_ln, kv_a_ln, cosp, sinp, qlatn, klatn, krot);
  // 4. q = qlatn @ Wqb^T with fused rope+scale+layout -> Qb (2048 x 6144, K=1536)
  gemm_qb<<<dim3(16 * 48, 1), 256, 0, stream>>>(qlatn, Wqb, cosp, sinp, Qb, 2048, 6144, 1536, 1536, 1536);
  // 5. kv = klatn @ Wkvb^T with fused split+transpose -> Knope, Vt (bf16)
  gemm_kvb<<<dim3(16 * 64, 1), 256, 0, stream>>>(klatn, Wkvb, Knope, Vt, 2048, 8192, 512, 512, 512);
  // 6. causal flash attention (exact R8/R12 known-good structure)
  flash_kernel<<<512, 256, 0, stream>>>(Qb, krot, Knope, Vt, attnb);
  // 7. out = attn @ Wo^T  (2048 x 4096, K=4096, fp32 out)
  gemm_ff<<<dim3(16 * 32, 1), 256, 0, stream>>>(attnb, Wo, out, 2048, 4096, 4096, 4096, 4096, 4096);
}